// Round 1
// baseline (867.442 us; speedup 1.0000x reference)
//
#include <hip/hip_runtime.h>
#include <hip/hip_bf16.h>
#include <math.h>

// Sizes (fixed by the problem)
#define BB   16
#define TT   512
#define HH   512
#define VV   4096
#define LL   64
#define SS   129           // 2*L+1
#define JJ   65            // distinct symbols per sample: blank + L labels
#define MM   (BB*TT)       // 8192 GEMM rows

#define NEGF (-1e30f)

__device__ __forceinline__ float lae(float a, float b) {
    float m = fmaxf(a, b);
    float d = fminf(a, b) - m;
    return m + log1pf(__expf(d));   // matches jnp.logaddexp (incl. both==NEG -> NEG+log2)
}

// ---------------------------------------------------------------------------
// Kernel 1: fp32 register-tiled GEMM fused with per-row logsumexp partials.
// C-tile 128x128, block 256 threads, each thread 8x8. Writes (rowmax, sumexp)
// per (row, n-tile) -- never materializes the 134MB logits tensor.
// ---------------------------------------------------------------------------
#define TM 128
#define TN 128
#define TK 16
#define NTILE (VV / TN)    // 32

__global__ __launch_bounds__(256) void gemm_lse_f32(
    const float* __restrict__ A,    // [M][512]  = hs_pad flattened
    const float* __restrict__ Bw,   // [512][4096] = W
    const float* __restrict__ bias, // [4096]
    float* __restrict__ part)       // [M][NTILE][2] (max, sumexp)
{
    const int K = HH, N = VV;
    __shared__ float As[TK][TM + 4];   // +4: keep rows 16B-aligned, dodge stride-128
    __shared__ float Bs[TK][TN + 4];
    const int tid = threadIdx.x;
    const int tx = tid & 15, ty = tid >> 4;
    const int m0 = blockIdx.y * TM, n0 = blockIdx.x * TN;

    float c[8][8];
    #pragma unroll
    for (int i = 0; i < 8; ++i)
        #pragma unroll
        for (int j = 0; j < 8; ++j) c[i][j] = 0.f;

    for (int k0 = 0; k0 < K; k0 += TK) {
        // Stage A: 128 rows x 16 k  (512 float4, 2 per thread), store transposed
        #pragma unroll
        for (int r = 0; r < 2; ++r) {
            int idx = tid + r * 256;
            int row = idx >> 2, kq = (idx & 3) << 2;
            float4 av = *(const float4*)&A[(size_t)(m0 + row) * K + k0 + kq];
            As[kq + 0][row] = av.x; As[kq + 1][row] = av.y;
            As[kq + 2][row] = av.z; As[kq + 3][row] = av.w;
        }
        // Stage B: 16 k x 128 n (coalesced 512B per 16 lanes)
        #pragma unroll
        for (int r = 0; r < 2; ++r) {
            int idx = tid + r * 256;
            int kb = idx >> 5, nq = (idx & 31) << 2;
            *(float4*)&Bs[kb][nq] = *(const float4*)&Bw[(size_t)(k0 + kb) * N + n0 + nq];
        }
        __syncthreads();
        #pragma unroll
        for (int kk = 0; kk < TK; ++kk) {
            float4 a0 = *(const float4*)&As[kk][ty * 8];
            float4 a1 = *(const float4*)&As[kk][ty * 8 + 4];
            float4 b0 = *(const float4*)&Bs[kk][tx * 8];
            float4 b1 = *(const float4*)&Bs[kk][tx * 8 + 4];
            float aa[8] = {a0.x, a0.y, a0.z, a0.w, a1.x, a1.y, a1.z, a1.w};
            float bb[8] = {b0.x, b0.y, b0.z, b0.w, b1.x, b1.y, b1.z, b1.w};
            #pragma unroll
            for (int i = 0; i < 8; ++i)
                #pragma unroll
                for (int j = 0; j < 8; ++j)
                    c[i][j] = fmaf(aa[i], bb[j], c[i][j]);
        }
        __syncthreads();
    }

    // Epilogue: add bias, per-row (over this 128-col tile) max + sum(exp)
    float bj[8];
    #pragma unroll
    for (int j = 0; j < 8; ++j) bj[j] = bias[n0 + tx * 8 + j];
    #pragma unroll
    for (int i = 0; i < 8; ++i) {
        float v[8];
        float mx = -3.4e38f;
        #pragma unroll
        for (int j = 0; j < 8; ++j) { v[j] = c[i][j] + bj[j]; mx = fmaxf(mx, v[j]); }
        #pragma unroll
        for (int d = 1; d < 16; d <<= 1) mx = fmaxf(mx, __shfl_xor(mx, d));
        float sm = 0.f;
        #pragma unroll
        for (int j = 0; j < 8; ++j) sm += __expf(v[j] - mx);
        #pragma unroll
        for (int d = 1; d < 16; d <<= 1) sm += __shfl_xor(sm, d);
        if (tx == 0) {
            size_t o = ((size_t)(m0 + ty * 8 + i) * NTILE + blockIdx.x) * 2;
            part[o] = mx; part[o + 1] = sm;
        }
    }
}

// ---------------------------------------------------------------------------
// Kernel 2: merge per-tile (max,sumexp) partials -> lse[row]
// ---------------------------------------------------------------------------
__global__ void lse_merge(const float* __restrict__ part, float* __restrict__ lse)
{
    int r = blockIdx.x * blockDim.x + threadIdx.x;
    if (r >= MM) return;
    const float* p = part + (size_t)r * NTILE * 2;
    float mx = -3.4e38f;
    #pragma unroll 4
    for (int nt = 0; nt < NTILE; ++nt) mx = fmaxf(mx, p[2 * nt]);
    float s = 0.f;
    #pragma unroll 4
    for (int nt = 0; nt < NTILE; ++nt) s += p[2 * nt + 1] * __expf(p[2 * nt] - mx);
    lse[r] = mx + logf(s);
}

// ---------------------------------------------------------------------------
// Kernel 3: gather needed W columns per sample: Wg[b][k][j] = W[k][col(b,j)]
// col(b,0)=blank=0, col(b,j)=ys_pad[b][j-1]
// ---------------------------------------------------------------------------
__global__ void gather_w(const float* __restrict__ W, const int* __restrict__ ys,
                         float* __restrict__ Wg)
{
    int idx = blockIdx.x * blockDim.x + threadIdx.x;
    const int total = BB * HH * JJ;
    if (idx >= total) return;
    int j = idx % JJ;
    int k = (idx / JJ) % HH;
    int b = idx / (JJ * HH);
    int col = (j == 0) ? 0 : ys[b * LL + (j - 1)];
    Wg[idx] = W[(size_t)k * VV + col];
}

// ---------------------------------------------------------------------------
// Kernel 4: label log-probs glp[b][t][j] = hs[b,t,:]·Wg[b,:,j] + bias - lse
// Block handles (b, 16 t's); hs tile staged in LDS (32KB); Wg reads coalesced.
// ---------------------------------------------------------------------------
__global__ __launch_bounds__(256) void glp_kernel(
    const float* __restrict__ hs, const float* __restrict__ Wg,
    const float* __restrict__ bias, const int* __restrict__ ys,
    const float* __restrict__ lse, float* __restrict__ glp)
{
    const int b = blockIdx.y;
    const int t0 = blockIdx.x * 16;
    __shared__ float hsS[16][HH];
    const int tid = threadIdx.x;
    for (int i = tid; i < 16 * (HH / 4); i += 256) {
        int row = i >> 7, cq = (i & 127) << 2;
        *(float4*)&hsS[row][cq] =
            *(const float4*)&hs[((size_t)(b * TT + t0 + row)) * HH + cq];
    }
    __syncthreads();
    for (int item = tid; item < 16 * JJ; item += 256) {
        int tl = item / JJ, j = item % JJ;
        const float* wcol = Wg + (size_t)b * HH * JJ + j;
        float acc = 0.f;
        #pragma unroll 8
        for (int k = 0; k < HH; ++k) acc = fmaf(hsS[tl][k], wcol[(size_t)k * JJ], acc);
        int col = (j == 0) ? 0 : ys[b * LL + j - 1];
        int m = b * TT + t0 + tl;
        glp[(size_t)m * JJ + j] = acc + bias[col] - lse[m];
    }
}

// ---------------------------------------------------------------------------
// Kernel 5: CTC forward DP. One block per sample. alpha in LDS, 1 barrier/step,
// emission for t+1 prefetched during step t.
// ---------------------------------------------------------------------------
__global__ __launch_bounds__(256) void ctc_dp(
    const float* __restrict__ glp, const int* __restrict__ ys,
    const int* __restrict__ hs_lens, const int* __restrict__ ys_lens,
    float* __restrict__ nll)
{
    const int b = blockIdx.x;
    __shared__ float buf[2][SS + 3];
    const int s = threadIdx.x;
    const int Tin = hs_lens[b];
    const bool active = (s < SS);
    int jm = 0;
    bool skip = false;
    if (active && (s & 1)) {
        jm = (s + 1) >> 1;
        if (s >= 3) {
            int lj = (s - 1) >> 1;
            int cc = ys[b * LL + lj];
            int cp = ys[b * LL + lj - 1];
            skip = (cc != 0) && (cc != cp);
        }
    }
    const float* g = glp + (size_t)b * TT * JJ;
    if (active) buf[0][s] = (s <= 1) ? g[jm] : NEGF;   // t=0 init
    __syncthreads();
    int cur = 0;
    float e = (active && Tin > 1) ? g[JJ + jm] : NEGF; // emit for t=1
    for (int t = 1; t < Tin; ++t) {
        float enext = (active && (t + 1 < Tin)) ? g[(size_t)(t + 1) * JJ + jm] : NEGF;
        if (active) {
            float a  = buf[cur][s];
            float a1 = (s >= 1) ? buf[cur][s - 1] : NEGF;
            float comb = lae(a, a1);
            if (skip) comb = lae(comb, buf[cur][s - 2]);
            buf[cur ^ 1][s] = comb + e;
        }
        __syncthreads();
        cur ^= 1;
        e = enext;
    }
    if (s == 0) {
        int Ll = ys_lens[b];
        int sl = 2 * Ll;
        float ll = lae(buf[cur][sl], buf[cur][sl - 1]);
        nll[b] = -ll;
    }
}

// ---------------------------------------------------------------------------
// Kernel 6: finalize: out = sum(nll)/B
// ---------------------------------------------------------------------------
__global__ void finalize(const float* __restrict__ nll, float* __restrict__ out)
{
    float v = (threadIdx.x < BB) ? nll[threadIdx.x] : 0.f;
    #pragma unroll
    for (int d = 32; d >= 1; d >>= 1) v += __shfl_down(v, d);
    if (threadIdx.x == 0) out[0] = v / (float)BB;
}

// ---------------------------------------------------------------------------
extern "C" void kernel_launch(void* const* d_in, const int* in_sizes, int n_in,
                              void* d_out, int out_size, void* d_ws, size_t ws_size,
                              hipStream_t stream) {
    const float* hs      = (const float*)d_in[0];   // [16,512,512] f32
    const int*   hs_lens = (const int*)  d_in[1];   // [16]
    const int*   ys      = (const int*)  d_in[2];   // [16,64]
    const int*   ys_lens = (const int*)  d_in[3];   // [16]
    const float* W       = (const float*)d_in[4];   // [512,4096] f32
    const float* bias    = (const float*)d_in[5];   // [4096]
    float* out = (float*)d_out;

    float* ws   = (float*)d_ws;
    float* part = ws;                                   // M*NTILE*2  = 524288
    float* lse  = part + (size_t)MM * NTILE * 2;        // 8192
    float* Wg   = lse  + MM;                            // B*H*J = 532480
    float* glp  = Wg   + (size_t)BB * HH * JJ;          // B*T*J = 532480
    float* nll  = glp  + (size_t)BB * TT * JJ;          // 16

    gemm_lse_f32<<<dim3(VV / TN, MM / TM), 256, 0, stream>>>(hs, W, bias, part);
    lse_merge<<<(MM + 255) / 256, 256, 0, stream>>>(part, lse);
    gather_w<<<(BB * HH * JJ + 255) / 256, 256, 0, stream>>>(W, ys, Wg);
    glp_kernel<<<dim3(TT / 16, BB), 256, 0, stream>>>(hs, Wg, bias, ys, lse, glp);
    ctc_dp<<<BB, 256, 0, stream>>>(glp, ys, hs_lens, ys_lens, nll);
    finalize<<<1, 64, 0, stream>>>(nll, out);
}

// Round 3
// 697.455 us; speedup vs baseline: 1.2437x; 1.2437x over previous
//
#include <hip/hip_runtime.h>
#include <hip/hip_bf16.h>
#include <math.h>

// Sizes (fixed by the problem)
#define BB   16
#define TT   512
#define HH   512
#define VV   4096
#define LL   64
#define SS   129           // 2*L+1
#define JJ   65            // distinct symbols per sample: blank + L labels
#define MM   (BB*TT)       // 8192 GEMM rows

#define NEGF (-1e30f)

typedef __bf16 bf16;
typedef __attribute__((ext_vector_type(8))) __bf16 bf16x8;
typedef __attribute__((ext_vector_type(4))) float f32x4;

__device__ __forceinline__ float lae(float a, float b) {
    float m = fmaxf(a, b);
    float d = fminf(a, b) - m;
    return m + log1pf(__expf(d));   // matches jnp.logaddexp (incl. both==NEG -> NEG+log2)
}

// ---------------------------------------------------------------------------
// Kernel 0a: hs (fp32) -> Abf (bf16), same [M][K] layout
// ---------------------------------------------------------------------------
__global__ __launch_bounds__(256) void conv_hs(const float* __restrict__ hs,
                                               bf16* __restrict__ Abf)
{
    int idx = blockIdx.x * blockDim.x + threadIdx.x;   // one float4 per thread
    const int n4 = MM * HH / 4;
    if (idx >= n4) return;
    float4 v = ((const float4*)hs)[idx];
    bf16* o = Abf + (size_t)idx * 4;
    o[0] = (bf16)v.x; o[1] = (bf16)v.y; o[2] = (bf16)v.z; o[3] = (bf16)v.w;
}

// ---------------------------------------------------------------------------
// Kernel 0b: W [K][N] fp32 -> Wt [N][K] bf16 (transpose via LDS 64x64 tiles)
// ---------------------------------------------------------------------------
__global__ __launch_bounds__(256) void transpose_w(const float* __restrict__ W,
                                                   bf16* __restrict__ Wt)
{
    __shared__ float t[64][65];
    const int n0 = blockIdx.x * 64;   // 64 tiles along N
    const int k0 = blockIdx.y * 64;   // 8 tiles along K
    const int tid = threadIdx.x;
    #pragma unroll
    for (int i = 0; i < 16; ++i) {
        int idx = tid + i * 256;
        int kk = idx >> 6, nn = idx & 63;
        t[kk][nn] = W[(size_t)(k0 + kk) * VV + n0 + nn];
    }
    __syncthreads();
    #pragma unroll
    for (int i = 0; i < 16; ++i) {
        int idx = tid + i * 256;
        int nl = idx >> 6, kk = idx & 63;
        Wt[(size_t)(n0 + nl) * HH + k0 + kk] = (bf16)t[kk][nl];
    }
}

// ---------------------------------------------------------------------------
// Kernel 1: bf16 MFMA GEMM fused with per-row logsumexp partials.
// 128x128 tile, BK=32, 4 waves (2x2), 16x16x32 MFMA, global_load_lds width 16,
// slot-XOR swizzle (pre-swizzled global source + swizzled ds_read).
// RACE FIX (r3): partials are per-64-column tile, index = blockIdx.x*2 + wn,
// so the two wn waves (disjoint column halves) never write the same slot.
// ---------------------------------------------------------------------------
#define TN 128
#define NT64 (VV / 64)     // 64 column-tiles of width 64

#define GLDS(src, dst) \
    __builtin_amdgcn_global_load_lds((const __attribute__((address_space(1))) void*)(src), \
                                     (__attribute__((address_space(3))) void*)(dst), 16, 0, 0)

__global__ __launch_bounds__(256) void gemm_lse_mfma(
    const bf16* __restrict__ A,    // [M][512] bf16
    const bf16* __restrict__ Bt,   // [N=4096][512] bf16 (W transposed)
    const float* __restrict__ bias,
    float* __restrict__ part)      // [M][NT64][2] (max, sumexp)
{
    __shared__ bf16 As[128 * 32];
    __shared__ bf16 Bs[128 * 32];
    const int tid = threadIdx.x;
    const int lane = tid & 63;
    const int wid = tid >> 6;
    const int wm = wid >> 1, wn = wid & 1;
    const int m0 = blockIdx.y * 128, n0 = blockIdx.x * 128;
    const int lq = lane & 15, kg = lane >> 4;

    f32x4 acc[4][4];
    const f32x4 z = {0.f, 0.f, 0.f, 0.f};
    #pragma unroll
    for (int i = 0; i < 4; ++i)
        #pragma unroll
        for (int j = 0; j < 4; ++j) acc[i][j] = z;

    // staging geometry (per 16B chunk): row = c>>2, slot = c&3, src slot XOR'd
    const int c0 = tid;            // issue 0 chunk
    const int row0 = c0 >> 2, sl0 = (c0 & 3) ^ (row0 & 3);
    const int c1 = tid + 256;      // issue 1 chunk
    const int row1 = c1 >> 2, sl1 = (c1 & 3) ^ (row1 & 3);
    bf16* dstA0 = As + (size_t)(0 * 256 + (tid & 192)) * 8;
    bf16* dstA1 = As + (size_t)(1 * 256 + (tid & 192)) * 8;
    bf16* dstB0 = Bs + (size_t)(0 * 256 + (tid & 192)) * 8;
    bf16* dstB1 = Bs + (size_t)(1 * 256 + (tid & 192)) * 8;
    const bf16* srcA0 = A  + (size_t)(m0 + row0) * HH + sl0 * 8;
    const bf16* srcA1 = A  + (size_t)(m0 + row1) * HH + sl1 * 8;
    const bf16* srcB0 = Bt + (size_t)(n0 + row0) * HH + sl0 * 8;
    const bf16* srcB1 = Bt + (size_t)(n0 + row1) * HH + sl1 * 8;

    for (int k0 = 0; k0 < HH; k0 += 32) {
        GLDS(srcA0 + k0, dstA0);
        GLDS(srcA1 + k0, dstA1);
        GLDS(srcB0 + k0, dstB0);
        GLDS(srcB1 + k0, dstB1);
        __syncthreads();   // vmcnt(0) drained by compiler before barrier
        bf16x8 a[4], b[4];
        #pragma unroll
        for (int i = 0; i < 4; ++i) {
            int ar = wm * 64 + i * 16 + lq;
            a[i] = *(const bf16x8*)&As[ar * 32 + ((kg ^ (ar & 3)) * 8)];
        }
        #pragma unroll
        for (int j = 0; j < 4; ++j) {
            int br = wn * 64 + j * 16 + lq;
            b[j] = *(const bf16x8*)&Bs[br * 32 + ((kg ^ (br & 3)) * 8)];
        }
        #pragma unroll
        for (int i = 0; i < 4; ++i)
            #pragma unroll
            for (int j = 0; j < 4; ++j)
                acc[i][j] = __builtin_amdgcn_mfma_f32_16x16x32_bf16(a[i], b[j], acc[i][j], 0, 0, 0);
        __syncthreads();
    }

    // Epilogue: bias + per-row (this wave's 64-col half) max / sumexp.
    // C/D layout: col = lane&15, row = (lane>>4)*4 + reg
    const int ct = blockIdx.x * 2 + wn;   // 64-col tile index
    float bj[4];
    #pragma unroll
    for (int j = 0; j < 4; ++j) bj[j] = bias[n0 + wn * 64 + j * 16 + lq];
    #pragma unroll
    for (int i = 0; i < 4; ++i) {
        #pragma unroll
        for (int r = 0; r < 4; ++r) {
            float v[4], mx = -3.4e38f;
            #pragma unroll
            for (int j = 0; j < 4; ++j) { v[j] = acc[i][j][r] + bj[j]; mx = fmaxf(mx, v[j]); }
            #pragma unroll
            for (int d = 1; d < 16; d <<= 1) mx = fmaxf(mx, __shfl_xor(mx, d));
            float sm = 0.f;
            #pragma unroll
            for (int j = 0; j < 4; ++j) sm += __expf(v[j] - mx);
            #pragma unroll
            for (int d = 1; d < 16; d <<= 1) sm += __shfl_xor(sm, d);
            if (lq == 0) {
                int rowg = m0 + wm * 64 + i * 16 + kg * 4 + r;
                size_t o = ((size_t)rowg * NT64 + ct) * 2;
                part[o] = mx; part[o + 1] = sm;
            }
        }
    }
}

// ---------------------------------------------------------------------------
// Kernel 2: merge per-tile (max,sumexp) partials -> lse[row]
// ---------------------------------------------------------------------------
__global__ void lse_merge(const float* __restrict__ part, float* __restrict__ lse)
{
    int r = blockIdx.x * blockDim.x + threadIdx.x;
    if (r >= MM) return;
    const float* p = part + (size_t)r * NT64 * 2;
    float mx = -3.4e38f;
    #pragma unroll 4
    for (int nt = 0; nt < NT64; ++nt) mx = fmaxf(mx, p[2 * nt]);
    float s = 0.f;
    #pragma unroll 4
    for (int nt = 0; nt < NT64; ++nt) s += p[2 * nt + 1] * __expf(p[2 * nt] - mx);
    lse[r] = mx + logf(s);
}

// ---------------------------------------------------------------------------
// Kernel 3: gather needed W columns per sample: Wg[b][k][j] = W[k][col(b,j)]
// ---------------------------------------------------------------------------
__global__ void gather_w(const float* __restrict__ W, const int* __restrict__ ys,
                         float* __restrict__ Wg)
{
    int idx = blockIdx.x * blockDim.x + threadIdx.x;
    const int total = BB * HH * JJ;
    if (idx >= total) return;
    int j = idx % JJ;
    int k = (idx / JJ) % HH;
    int b = idx / (JJ * HH);
    int col = (j == 0) ? 0 : ys[b * LL + (j - 1)];
    Wg[idx] = W[(size_t)k * VV + col];
}

// ---------------------------------------------------------------------------
// Kernel 4: label log-probs glp[b][t][j] = hs[b,t,:]·Wg[b,:,j] + bias - lse
// ---------------------------------------------------------------------------
__global__ __launch_bounds__(256) void glp_kernel(
    const float* __restrict__ hs, const float* __restrict__ Wg,
    const float* __restrict__ bias, const int* __restrict__ ys,
    const float* __restrict__ lse, float* __restrict__ glp)
{
    const int b = blockIdx.y;
    const int t0 = blockIdx.x * 16;
    __shared__ float hsS[16][HH];
    const int tid = threadIdx.x;
    for (int i = tid; i < 16 * (HH / 4); i += 256) {
        int row = i >> 7, cq = (i & 127) << 2;
        *(float4*)&hsS[row][cq] =
            *(const float4*)&hs[((size_t)(b * TT + t0 + row)) * HH + cq];
    }
    __syncthreads();
    for (int item = tid; item < 16 * JJ; item += 256) {
        int tl = item / JJ, j = item % JJ;
        const float* wcol = Wg + (size_t)b * HH * JJ + j;
        float acc = 0.f;
        #pragma unroll 8
        for (int k = 0; k < HH; ++k) acc = fmaf(hsS[tl][k], wcol[(size_t)k * JJ], acc);
        int col = (j == 0) ? 0 : ys[b * LL + j - 1];
        int m = b * TT + t0 + tl;
        glp[(size_t)m * JJ + j] = acc + bias[col] - lse[m];
    }
}

// ---------------------------------------------------------------------------
// Kernel 5: CTC forward DP, fully in registers. One wave per sample.
// Lane l holds A=alpha[2l] (blank state, no skip) and B=alpha[2l+1] (label);
// lane 63 additionally maintains C=alpha[128]. One shfl_up per step.
// ---------------------------------------------------------------------------
__global__ __launch_bounds__(64) void ctc_dp(
    const float* __restrict__ glp, const int* __restrict__ ys,
    const int* __restrict__ hs_lens, const int* __restrict__ ys_lens,
    float* __restrict__ nll)
{
    const int b = blockIdx.x;
    const int l = threadIdx.x;          // 0..63
    const float* g = glp + (size_t)b * TT * JJ;
    const int Tin = hs_lens[b];

    int cc = ys[b * LL + l];
    bool skipB = false;
    if (l >= 1) { int cp = ys[b * LL + l - 1]; skipB = (cc != 0) && (cc != cp); }

    float A = (l == 0) ? g[0] : NEGF;   // alpha[0] = emit blank
    float B = (l == 0) ? g[1] : NEGF;   // alpha[1] = emit label0
    float C = NEGF;                      // alpha[128] (lane 63)

    float e0  = g[JJ];                   // blank emission, row t=1
    float eB  = g[JJ + l + 1];           // label emission, row t=1
    for (int t = 1; t < Tin; ++t) {
        float e0n = 0.f, eBn = 0.f;
        if (t + 1 < Tin) {               // prefetch next row
            e0n = g[(size_t)(t + 1) * JJ];
            eBn = g[(size_t)(t + 1) * JJ + l + 1];
        }
        float prevB = __shfl_up(B, 1, 64);
        if (l == 0) prevB = NEGF;
        float nA = lae(A, prevB) + e0;                    // even s: no skip
        float nB = lae(lae(B, A), skipB ? prevB : NEGF) + eB;
        float nC = lae(C, B) + e0;                        // valid on lane 63
        A = nA; B = nB; C = nC;
        e0 = e0n; eB = eBn;
    }
    int Ll = ys_lens[b];                 // 32..64
    float v1 = (Ll == 64) ? __shfl(C, 63, 64) : __shfl(A, Ll, 64);  // alpha[2Ll]
    float v2 = __shfl(B, Ll - 1, 64);                                // alpha[2Ll-1]
    if (l == 0) nll[b] = -lae(v1, v2);
}

// ---------------------------------------------------------------------------
// Kernel 6: finalize: out = sum(nll)/B
// ---------------------------------------------------------------------------
__global__ void finalize(const float* __restrict__ nll, float* __restrict__ out)
{
    float v = (threadIdx.x < BB) ? nll[threadIdx.x] : 0.f;
    #pragma unroll
    for (int d = 32; d >= 1; d >>= 1) v += __shfl_down(v, d);
    if (threadIdx.x == 0) out[0] = v / (float)BB;
}

// ---------------------------------------------------------------------------
extern "C" void kernel_launch(void* const* d_in, const int* in_sizes, int n_in,
                              void* d_out, int out_size, void* d_ws, size_t ws_size,
                              hipStream_t stream) {
    const float* hs      = (const float*)d_in[0];   // [16,512,512] f32
    const int*   hs_lens = (const int*)  d_in[1];   // [16]
    const int*   ys      = (const int*)  d_in[2];   // [16,64]
    const int*   ys_lens = (const int*)  d_in[3];   // [16]
    const float* W       = (const float*)d_in[4];   // [512,4096] f32
    const float* bias    = (const float*)d_in[5];   // [4096]
    float* out = (float*)d_out;

    float* ws   = (float*)d_ws;
    float* part = ws;                                   // M*NT64*2 = 1048576 f
    float* lse  = part + (size_t)MM * NT64 * 2;         // 8192 f
    float* Wg   = lse  + MM;                            // 532480 f
    float* glp  = Wg   + (size_t)BB * HH * JJ;          // 532480 f
    float* nll  = glp  + (size_t)BB * TT * JJ;          // 16 f
    bf16*  Abf  = (bf16*)(nll + 16);                    // 4194304 bf16
    bf16*  Wt   = Abf + (size_t)MM * HH;                // 2097152 bf16

    conv_hs<<<(MM * HH / 4 + 255) / 256, 256, 0, stream>>>(hs, Abf);
    transpose_w<<<dim3(VV / 64, HH / 64), 256, 0, stream>>>(W, Wt);
    gemm_lse_mfma<<<dim3(VV / TN, MM / 128), 256, 0, stream>>>(Abf, Wt, bias, part);
    lse_merge<<<(MM + 255) / 256, 256, 0, stream>>>(part, lse);
    gather_w<<<(BB * HH * JJ + 255) / 256, 256, 0, stream>>>(W, ys, Wg);
    glp_kernel<<<dim3(TT / 16, BB), 256, 0, stream>>>(hs, Wg, bias, ys, lse, glp);
    ctc_dp<<<BB, 64, 0, stream>>>(glp, ys, hs_lens, ys_lens, nll);
    finalize<<<1, 64, 0, stream>>>(nll, out);
}

// Round 4
// 298.280 us; speedup vs baseline: 2.9081x; 2.3383x over previous
//
#include <hip/hip_runtime.h>
#include <hip/hip_bf16.h>
#include <math.h>

// Sizes (fixed by the problem)
#define BB   16
#define TT   512
#define HH   512
#define VV   4096
#define LL   64
#define SS   129           // 2*L+1
#define JJ   65            // distinct symbols per sample: blank + L labels
#define MM   (BB*TT)       // 8192 GEMM rows

#define NEGF (-1e30f)
#define LOG2E 1.4426950408889634f
#define LN2   0.6931471805599453f

typedef __bf16 bf16;
typedef __attribute__((ext_vector_type(8))) __bf16 bf16x8;
typedef __attribute__((ext_vector_type(4))) float f32x4;

__device__ __forceinline__ float lae(float a, float b) {   // natural-log domain
    float m = fmaxf(a, b);
    float d = fminf(a, b) - m;
    return m + log1pf(__expf(d));
}

// log2-domain logaddexp: m + log2(1 + 2^(min-max)); v_exp_f32/v_log_f32 only
__device__ __forceinline__ float lae2(float a, float b) {
    float m = fmaxf(a, b);
    float d = fminf(a, b) - m;
    return m + __log2f(1.0f + exp2f(d));
}
// 3-way log2-domain logaddexp
__device__ __forceinline__ float lae2_3(float a, float b, float c) {
    float m = fmaxf(fmaxf(a, b), c);
    float s = exp2f(a - m) + exp2f(b - m) + exp2f(c - m);
    return m + __log2f(s);
}

// shfl_up by 1 across the full wave via DPP wave_shr:1; lane0 -> NEGF
__device__ __forceinline__ float shfl_up1_neg(float x) {
    int r = __builtin_amdgcn_update_dpp(__float_as_int(NEGF), __float_as_int(x),
                                        0x138 /*wave_shr:1*/, 0xF, 0xF, false);
    return __int_as_float(r);
}

// ---------------------------------------------------------------------------
// Kernel 0a: hs (fp32) -> Abf (bf16), same [M][K] layout
// ---------------------------------------------------------------------------
__global__ __launch_bounds__(256) void conv_hs(const float* __restrict__ hs,
                                               bf16* __restrict__ Abf)
{
    int idx = blockIdx.x * blockDim.x + threadIdx.x;   // one float4 per thread
    const int n4 = MM * HH / 4;
    if (idx >= n4) return;
    float4 v = ((const float4*)hs)[idx];
    bf16* o = Abf + (size_t)idx * 4;
    o[0] = (bf16)v.x; o[1] = (bf16)v.y; o[2] = (bf16)v.z; o[3] = (bf16)v.w;
}

// ---------------------------------------------------------------------------
// Kernel 0b: W [K][N] fp32 -> Wt [N][K] bf16 (transpose via LDS 64x64 tiles)
// ---------------------------------------------------------------------------
__global__ __launch_bounds__(256) void transpose_w(const float* __restrict__ W,
                                                   bf16* __restrict__ Wt)
{
    __shared__ float t[64][65];
    const int n0 = blockIdx.x * 64;
    const int k0 = blockIdx.y * 64;
    const int tid = threadIdx.x;
    #pragma unroll
    for (int i = 0; i < 16; ++i) {
        int idx = tid + i * 256;
        int kk = idx >> 6, nn = idx & 63;
        t[kk][nn] = W[(size_t)(k0 + kk) * VV + n0 + nn];
    }
    __syncthreads();
    #pragma unroll
    for (int i = 0; i < 16; ++i) {
        int idx = tid + i * 256;
        int nl = idx >> 6, kk = idx & 63;
        Wt[(size_t)(n0 + nl) * HH + k0 + kk] = (bf16)t[kk][nl];
    }
}

// ---------------------------------------------------------------------------
// Kernel 1: bf16 MFMA GEMM fused with per-row logsumexp partials.
// (unchanged from r3 — verified)
// ---------------------------------------------------------------------------
#define TN 128
#define NT64 (VV / 64)     // 64 column-tiles of width 64

#define GLDS(src, dst) \
    __builtin_amdgcn_global_load_lds((const __attribute__((address_space(1))) void*)(src), \
                                     (__attribute__((address_space(3))) void*)(dst), 16, 0, 0)

__global__ __launch_bounds__(256) void gemm_lse_mfma(
    const bf16* __restrict__ A,    // [M][512] bf16
    const bf16* __restrict__ Bt,   // [N=4096][512] bf16 (W transposed)
    const float* __restrict__ bias,
    float* __restrict__ part)      // [M][NT64][2] (max, sumexp)
{
    __shared__ bf16 As[128 * 32];
    __shared__ bf16 Bs[128 * 32];
    const int tid = threadIdx.x;
    const int lane = tid & 63;
    const int wid = tid >> 6;
    const int wm = wid >> 1, wn = wid & 1;
    const int m0 = blockIdx.y * 128, n0 = blockIdx.x * 128;
    const int lq = lane & 15, kg = lane >> 4;

    f32x4 acc[4][4];
    const f32x4 z = {0.f, 0.f, 0.f, 0.f};
    #pragma unroll
    for (int i = 0; i < 4; ++i)
        #pragma unroll
        for (int j = 0; j < 4; ++j) acc[i][j] = z;

    const int c0 = tid;
    const int row0 = c0 >> 2, sl0 = (c0 & 3) ^ (row0 & 3);
    const int c1 = tid + 256;
    const int row1 = c1 >> 2, sl1 = (c1 & 3) ^ (row1 & 3);
    bf16* dstA0 = As + (size_t)(0 * 256 + (tid & 192)) * 8;
    bf16* dstA1 = As + (size_t)(1 * 256 + (tid & 192)) * 8;
    bf16* dstB0 = Bs + (size_t)(0 * 256 + (tid & 192)) * 8;
    bf16* dstB1 = Bs + (size_t)(1 * 256 + (tid & 192)) * 8;
    const bf16* srcA0 = A  + (size_t)(m0 + row0) * HH + sl0 * 8;
    const bf16* srcA1 = A  + (size_t)(m0 + row1) * HH + sl1 * 8;
    const bf16* srcB0 = Bt + (size_t)(n0 + row0) * HH + sl0 * 8;
    const bf16* srcB1 = Bt + (size_t)(n0 + row1) * HH + sl1 * 8;

    for (int k0 = 0; k0 < HH; k0 += 32) {
        GLDS(srcA0 + k0, dstA0);
        GLDS(srcA1 + k0, dstA1);
        GLDS(srcB0 + k0, dstB0);
        GLDS(srcB1 + k0, dstB1);
        __syncthreads();
        bf16x8 a[4], b[4];
        #pragma unroll
        for (int i = 0; i < 4; ++i) {
            int ar = wm * 64 + i * 16 + lq;
            a[i] = *(const bf16x8*)&As[ar * 32 + ((kg ^ (ar & 3)) * 8)];
        }
        #pragma unroll
        for (int j = 0; j < 4; ++j) {
            int br = wn * 64 + j * 16 + lq;
            b[j] = *(const bf16x8*)&Bs[br * 32 + ((kg ^ (br & 3)) * 8)];
        }
        #pragma unroll
        for (int i = 0; i < 4; ++i)
            #pragma unroll
            for (int j = 0; j < 4; ++j)
                acc[i][j] = __builtin_amdgcn_mfma_f32_16x16x32_bf16(a[i], b[j], acc[i][j], 0, 0, 0);
        __syncthreads();
    }

    const int ct = blockIdx.x * 2 + wn;   // 64-col tile index (race-free)
    float bj[4];
    #pragma unroll
    for (int j = 0; j < 4; ++j) bj[j] = bias[n0 + wn * 64 + j * 16 + lq];
    #pragma unroll
    for (int i = 0; i < 4; ++i) {
        #pragma unroll
        for (int r = 0; r < 4; ++r) {
            float v[4], mx = -3.4e38f;
            #pragma unroll
            for (int j = 0; j < 4; ++j) { v[j] = acc[i][j][r] + bj[j]; mx = fmaxf(mx, v[j]); }
            #pragma unroll
            for (int d = 1; d < 16; d <<= 1) mx = fmaxf(mx, __shfl_xor(mx, d));
            float sm = 0.f;
            #pragma unroll
            for (int j = 0; j < 4; ++j) sm += __expf(v[j] - mx);
            #pragma unroll
            for (int d = 1; d < 16; d <<= 1) sm += __shfl_xor(sm, d);
            if (lq == 0) {
                int rowg = m0 + wm * 64 + i * 16 + kg * 4 + r;
                size_t o = ((size_t)rowg * NT64 + ct) * 2;
                part[o] = mx; part[o + 1] = sm;
            }
        }
    }
}

// ---------------------------------------------------------------------------
// Kernel 2: merge per-tile (max,sumexp) partials -> lse[row]
// ---------------------------------------------------------------------------
__global__ void lse_merge(const float* __restrict__ part, float* __restrict__ lse)
{
    int r = blockIdx.x * blockDim.x + threadIdx.x;
    if (r >= MM) return;
    const float* p = part + (size_t)r * NT64 * 2;
    float mx = -3.4e38f;
    #pragma unroll 4
    for (int nt = 0; nt < NT64; ++nt) mx = fmaxf(mx, p[2 * nt]);
    float s = 0.f;
    #pragma unroll 4
    for (int nt = 0; nt < NT64; ++nt) s += p[2 * nt + 1] * __expf(p[2 * nt] - mx);
    lse[r] = mx + logf(s);
}

// ---------------------------------------------------------------------------
// Kernel 3: gather needed W columns per sample: Wg[b][k][j] = W[k][col(b,j)]
// ---------------------------------------------------------------------------
__global__ void gather_w(const float* __restrict__ W, const int* __restrict__ ys,
                         float* __restrict__ Wg)
{
    int idx = blockIdx.x * blockDim.x + threadIdx.x;
    const int total = BB * HH * JJ;
    if (idx >= total) return;
    int j = idx % JJ;
    int k = (idx / JJ) % HH;
    int b = idx / (JJ * HH);
    int col = (j == 0) ? 0 : ys[b * LL + (j - 1)];
    Wg[idx] = W[(size_t)k * VV + col];
}

// ---------------------------------------------------------------------------
// Kernel 4: label log-probs, now emitted in LOG2 domain:
// glp2[b][t][j] = (hs·Wg + bias - lse) * log2(e)
// ---------------------------------------------------------------------------
__global__ __launch_bounds__(256) void glp_kernel(
    const float* __restrict__ hs, const float* __restrict__ Wg,
    const float* __restrict__ bias, const int* __restrict__ ys,
    const float* __restrict__ lse, float* __restrict__ glp)
{
    const int b = blockIdx.y;
    const int t0 = blockIdx.x * 16;
    __shared__ float hsS[16][HH];
    const int tid = threadIdx.x;
    for (int i = tid; i < 16 * (HH / 4); i += 256) {
        int row = i >> 7, cq = (i & 127) << 2;
        *(float4*)&hsS[row][cq] =
            *(const float4*)&hs[((size_t)(b * TT + t0 + row)) * HH + cq];
    }
    __syncthreads();
    for (int item = tid; item < 16 * JJ; item += 256) {
        int tl = item / JJ, j = item % JJ;
        const float* wcol = Wg + (size_t)b * HH * JJ + j;
        float acc = 0.f;
        #pragma unroll 8
        for (int k = 0; k < HH; ++k) acc = fmaf(hsS[tl][k], wcol[(size_t)k * JJ], acc);
        int col = (j == 0) ? 0 : ys[b * LL + j - 1];
        int m = b * TT + t0 + tl;
        glp[(size_t)m * JJ + j] = (acc + bias[col] - lse[m]) * LOG2E;
    }
}

// ---------------------------------------------------------------------------
// Kernel 5: CTC forward DP, registers only, log2 domain.
// Lane l: A=alpha[2l] (blank), B=alpha[2l+1] (label l); lane63 also C=alpha[128].
// prevB via DPP wave_shr:1 (2 cyc, no LDS). Emissions preloaded 16 steps ahead,
// double-buffered register arrays (statically unrolled). All 512 steps run;
// freeze-select keeps alpha fixed for t >= Tin.
// ---------------------------------------------------------------------------
#define LOADCH(e0v, ebv, tbase) \
    _Pragma("unroll") \
    for (int u = 0; u < 16; ++u) { \
        int tt = (tbase) + u; tt = tt < TT ? tt : (TT - 1); \
        e0v[u] = g[tt * JJ]; \
        ebv[u] = g[tt * JJ + l + 1]; \
    }

#define STEPCH(e0v, ebv, tbase) \
    _Pragma("unroll") \
    for (int u = 0; u < 16; ++u) { \
        int t = (tbase) + u; \
        float prevB = shfl_up1_neg(B); \
        float nA = lae2(A, prevB) + e0v[u]; \
        float nB = lae2_3(B, A, skipB ? prevB : NEGF) + ebv[u]; \
        float nC = lae2(C, B) + e0v[u]; \
        bool upd = t < Tin; \
        A = upd ? nA : A; B = upd ? nB : B; C = upd ? nC : C; \
    }

__global__ __launch_bounds__(64) void ctc_dp(
    const float* __restrict__ glp, const int* __restrict__ ys,
    const int* __restrict__ hs_lens, const int* __restrict__ ys_lens,
    float* __restrict__ nll)
{
    const int b = blockIdx.x;
    const int l = threadIdx.x;          // 0..63
    const float* g = glp + (size_t)b * TT * JJ;
    const int Tin = hs_lens[b];

    int cc = ys[b * LL + l];
    bool skipB = false;
    if (l >= 1) { int cp = ys[b * LL + l - 1]; skipB = (cc != 0) && (cc != cp); }

    float A = (l == 0) ? g[0] : NEGF;   // alpha[0]
    float B = (l == 0) ? g[1] : NEGF;   // alpha[1]
    float C = NEGF;                      // alpha[128] (lane 63)

    float e0a[16], eba[16], e0b[16], ebb[16];
    LOADCH(e0a, eba, 1);
    for (int tc = 1; tc < 513; tc += 32) {
        LOADCH(e0b, ebb, tc + 16);
        STEPCH(e0a, eba, tc);
        LOADCH(e0a, eba, tc + 32);
        STEPCH(e0b, ebb, tc + 16);
    }

    int Ll = ys_lens[b];                 // 32..64
    float v1 = (Ll == 64) ? __shfl(C, 63, 64) : __shfl(A, Ll, 64);  // alpha[2Ll]
    float v2 = __shfl(B, Ll - 1, 64);                                // alpha[2Ll-1]
    if (l == 0) nll[b] = -lae2(v1, v2) * LN2;   // back to natural log
}

// ---------------------------------------------------------------------------
// Kernel 6: finalize: out = sum(nll)/B
// ---------------------------------------------------------------------------
__global__ void finalize(const float* __restrict__ nll, float* __restrict__ out)
{
    float v = (threadIdx.x < BB) ? nll[threadIdx.x] : 0.f;
    #pragma unroll
    for (int d = 32; d >= 1; d >>= 1) v += __shfl_down(v, d);
    if (threadIdx.x == 0) out[0] = v / (float)BB;
}

// ---------------------------------------------------------------------------
extern "C" void kernel_launch(void* const* d_in, const int* in_sizes, int n_in,
                              void* d_out, int out_size, void* d_ws, size_t ws_size,
                              hipStream_t stream) {
    const float* hs      = (const float*)d_in[0];   // [16,512,512] f32
    const int*   hs_lens = (const int*)  d_in[1];   // [16]
    const int*   ys      = (const int*)  d_in[2];   // [16,64]
    const int*   ys_lens = (const int*)  d_in[3];   // [16]
    const float* W       = (const float*)d_in[4];   // [512,4096] f32
    const float* bias    = (const float*)d_in[5];   // [4096]
    float* out = (float*)d_out;

    float* ws   = (float*)d_ws;
    float* part = ws;                                   // M*NT64*2 = 1048576 f
    float* lse  = part + (size_t)MM * NT64 * 2;         // 8192 f
    float* Wg   = lse  + MM;                            // 532480 f
    float* glp  = Wg   + (size_t)BB * HH * JJ;          // 532480 f
    float* nll  = glp  + (size_t)BB * TT * JJ;          // 16 f
    bf16*  Abf  = (bf16*)(nll + 16);                    // 4194304 bf16
    bf16*  Wt   = Abf + (size_t)MM * HH;                // 2097152 bf16

    conv_hs<<<(MM * HH / 4 + 255) / 256, 256, 0, stream>>>(hs, Abf);
    transpose_w<<<dim3(VV / 64, HH / 64), 256, 0, stream>>>(W, Wt);
    gemm_lse_mfma<<<dim3(VV / TN, MM / 128), 256, 0, stream>>>(Abf, Wt, bias, part);
    lse_merge<<<(MM + 255) / 256, 256, 0, stream>>>(part, lse);
    gather_w<<<(BB * HH * JJ + 255) / 256, 256, 0, stream>>>(W, ys, Wg);
    glp_kernel<<<dim3(TT / 16, BB), 256, 0, stream>>>(hs, Wg, bias, ys, lse, glp);
    ctc_dp<<<BB, 64, 0, stream>>>(glp, ys, hs_lens, ys_lens, nll);
    finalize<<<1, 64, 0, stream>>>(nll, out);
}

// Round 8
// 207.732 us; speedup vs baseline: 4.1758x; 1.4359x over previous
//
#include <hip/hip_runtime.h>
#include <hip/hip_bf16.h>
#include <math.h>

// Sizes (fixed by the problem)
#define BB   16
#define TT   512
#define HH   512
#define VV   4096
#define LL   64
#define SS   129           // 2*L+1
#define JJ   65            // distinct symbols per sample: blank + L labels
#define MM   (BB*TT)       // 8192 GEMM rows

#define LOG2E 1.4426950408889634f
#define LN2   0.6931471805599453f

typedef __bf16 bf16;
typedef __attribute__((ext_vector_type(4))) __bf16 bf16x4;
typedef __attribute__((ext_vector_type(8))) __bf16 bf16x8;
typedef __attribute__((ext_vector_type(4))) float f32x4;

// ---------------------------------------------------------------------------
// Kernel 0a: hs (fp32) -> Abf (bf16), same [M][K] layout
// ---------------------------------------------------------------------------
__global__ __launch_bounds__(256) void conv_hs(const float* __restrict__ hs,
                                               bf16* __restrict__ Abf)
{
    int idx = blockIdx.x * blockDim.x + threadIdx.x;   // one float4 per thread
    const int n4 = MM * HH / 4;
    if (idx >= n4) return;
    float4 v = ((const float4*)hs)[idx];
    bf16x4 o = {(bf16)v.x, (bf16)v.y, (bf16)v.z, (bf16)v.w};
    *(bf16x4*)(Abf + (size_t)idx * 4) = o;
}

// ---------------------------------------------------------------------------
// Kernel 0b: W [K][N] fp32 -> Wt [N][K] bf16 (transpose via LDS 64x64 tiles)
// ---------------------------------------------------------------------------
__global__ __launch_bounds__(256) void transpose_w(const float* __restrict__ W,
                                                   bf16* __restrict__ Wt)
{
    __shared__ float t[64][65];
    const int n0 = blockIdx.x * 64;
    const int k0 = blockIdx.y * 64;
    const int tid = threadIdx.x;
    #pragma unroll
    for (int i = 0; i < 16; ++i) {
        int idx = tid + i * 256;
        int kk = idx >> 6, nn = idx & 63;
        t[kk][nn] = W[(size_t)(k0 + kk) * VV + n0 + nn];
    }
    __syncthreads();
    #pragma unroll
    for (int i = 0; i < 16; ++i) {
        int idx = tid + i * 256;
        int nl = idx >> 6, kk = idx & 63;
        Wt[(size_t)(n0 + nl) * HH + k0 + kk] = (bf16)t[kk][nl];
    }
}

// ---------------------------------------------------------------------------
// Kernel 0c: per-sample extended-label column map
// ---------------------------------------------------------------------------
__global__ void make_cmap(const int* __restrict__ ys, int* __restrict__ cmap)
{
    int idx = threadIdx.x + blockIdx.x * blockDim.x;
    if (idx >= BB * JJ) return;
    int b = idx / JJ, j = idx % JJ;
    cmap[idx] = (j == 0) ? 0 : ys[b * LL + j - 1];
}

// ---------------------------------------------------------------------------
// Kernel 1: bf16 MFMA GEMM fused with (a) per-row logsumexp partials and
// (b) scatter of the 65 label-column raw logits (+bias) per sample.
// ---------------------------------------------------------------------------
#define TN 128
#define NT64 (VV / 64)     // 64 column-tiles of width 64

#define GLDS(src, dst) \
    __builtin_amdgcn_global_load_lds((const __attribute__((address_space(1))) void*)(src), \
                                     (__attribute__((address_space(3))) void*)(dst), 16, 0, 0)

__global__ __launch_bounds__(256) void gemm_lse_mfma(
    const bf16* __restrict__ A,    // [M][512] bf16
    const bf16* __restrict__ Bt,   // [N=4096][512] bf16 (W transposed)
    const float* __restrict__ bias,
    const int*  __restrict__ cmap, // [BB][JJ]
    float* __restrict__ part,      // [M][NT64][2] (max, sumexp)
    float* __restrict__ glp_raw)   // [M][JJ] raw label logits + bias
{
    __shared__ bf16 As[128 * 32];
    __shared__ bf16 Bs[128 * 32];
    const int tid = threadIdx.x;
    const int lane = tid & 63;
    const int wid = tid >> 6;
    const int wm = wid >> 1, wn = wid & 1;
    const int m0 = blockIdx.y * 128, n0 = blockIdx.x * 128;
    const int lq = lane & 15, kg = lane >> 4;

    f32x4 acc[4][4];
    const f32x4 z = {0.f, 0.f, 0.f, 0.f};
    #pragma unroll
    for (int i = 0; i < 4; ++i)
        #pragma unroll
        for (int j = 0; j < 4; ++j) acc[i][j] = z;

    const int c0 = tid;
    const int row0 = c0 >> 2, sl0 = (c0 & 3) ^ (row0 & 3);
    const int c1 = tid + 256;
    const int row1 = c1 >> 2, sl1 = (c1 & 3) ^ (row1 & 3);
    bf16* dstA0 = As + (size_t)(0 * 256 + (tid & 192)) * 8;
    bf16* dstA1 = As + (size_t)(1 * 256 + (tid & 192)) * 8;
    bf16* dstB0 = Bs + (size_t)(0 * 256 + (tid & 192)) * 8;
    bf16* dstB1 = Bs + (size_t)(1 * 256 + (tid & 192)) * 8;
    const bf16* srcA0 = A  + (size_t)(m0 + row0) * HH + sl0 * 8;
    const bf16* srcA1 = A  + (size_t)(m0 + row1) * HH + sl1 * 8;
    const bf16* srcB0 = Bt + (size_t)(n0 + row0) * HH + sl0 * 8;
    const bf16* srcB1 = Bt + (size_t)(n0 + row1) * HH + sl1 * 8;

    for (int k0 = 0; k0 < HH; k0 += 32) {
        GLDS(srcA0 + k0, dstA0);
        GLDS(srcA1 + k0, dstA1);
        GLDS(srcB0 + k0, dstB0);
        GLDS(srcB1 + k0, dstB1);
        __syncthreads();
        bf16x8 a[4], b[4];
        #pragma unroll
        for (int i = 0; i < 4; ++i) {
            int ar = wm * 64 + i * 16 + lq;
            a[i] = *(const bf16x8*)&As[ar * 32 + ((kg ^ (ar & 3)) * 8)];
        }
        #pragma unroll
        for (int j = 0; j < 4; ++j) {
            int br = wn * 64 + j * 16 + lq;
            b[j] = *(const bf16x8*)&Bs[br * 32 + ((kg ^ (br & 3)) * 8)];
        }
        #pragma unroll
        for (int i = 0; i < 4; ++i)
            #pragma unroll
            for (int j = 0; j < 4; ++j)
                acc[i][j] = __builtin_amdgcn_mfma_f32_16x16x32_bf16(a[i], b[j], acc[i][j], 0, 0, 0);
        __syncthreads();
    }

    // ---- epilogue (a): bias + per-row (this wave's 64-col half) max/sumexp
    const int ct = blockIdx.x * 2 + wn;   // 64-col tile index (race-free)
    float bj[4];
    #pragma unroll
    for (int j = 0; j < 4; ++j) bj[j] = bias[n0 + wn * 64 + j * 16 + lq];
    #pragma unroll
    for (int i = 0; i < 4; ++i) {
        #pragma unroll
        for (int r = 0; r < 4; ++r) {
            float v[4], mx = -3.4e38f;
            #pragma unroll
            for (int j = 0; j < 4; ++j) { v[j] = acc[i][j][r] + bj[j]; mx = fmaxf(mx, v[j]); }
            #pragma unroll
            for (int d = 1; d < 16; d <<= 1) mx = fmaxf(mx, __shfl_xor(mx, d));
            float sm = 0.f;
            #pragma unroll
            for (int j = 0; j < 4; ++j) sm += __expf(v[j] - mx);
            #pragma unroll
            for (int d = 1; d < 16; d <<= 1) sm += __shfl_xor(sm, d);
            if (lq == 0) {
                int rowg = m0 + wm * 64 + i * 16 + kg * 4 + r;
                size_t o = ((size_t)rowg * NT64 + ct) * 2;
                part[o] = mx; part[o + 1] = sm;
            }
        }
    }

    // ---- epilogue (b): scatter label columns (raw logit + bias)
    const int bidx  = m0 >> 9;              // sample (512 rows per sample)
    const int nbase = n0 + wn * 64;
    for (int j = 0; j < JJ; ++j) {
        int c = cmap[bidx * JJ + j];        // uniform
        int local = c - nbase;
        if (local >= 0 && local < 64) {     // uniform branch (~2 hits/wave)
            int cl = local & 15;
            float bc = bias[c];
            #pragma unroll
            for (int jt = 0; jt < 4; ++jt) {   // static jt: keep acc in regs
                if ((local >> 4) == jt && lq == cl) {
                    #pragma unroll
                    for (int i = 0; i < 4; ++i)
                        #pragma unroll
                        for (int r = 0; r < 4; ++r) {
                            int m = m0 + wm * 64 + i * 16 + kg * 4 + r;
                            glp_raw[(size_t)m * JJ + j] = acc[i][jt][r] + bc;
                        }
                }
            }
        }
    }
}

// ---------------------------------------------------------------------------
// Kernel 2: merge per-tile (max,sumexp) partials -> lse[row]
// ---------------------------------------------------------------------------
__global__ void lse_merge(const float* __restrict__ part, float* __restrict__ lse)
{
    int r = blockIdx.x * blockDim.x + threadIdx.x;
    if (r >= MM) return;
    const float* p = part + (size_t)r * NT64 * 2;
    float mx = -3.4e38f;
    #pragma unroll 4
    for (int nt = 0; nt < NT64; ++nt) mx = fmaxf(mx, p[2 * nt]);
    float s = 0.f;
    #pragma unroll 4
    for (int nt = 0; nt < NT64; ++nt) s += p[2 * nt + 1] * __expf(p[2 * nt] - mx);
    lse[r] = mx + logf(s);
}

// ---------------------------------------------------------------------------
// Kernel 5: CTC forward DP, linear domain with exact power-of-2 rescaling.
// UNDERFLOW FIX (r8): rescale max is over VALID states only (s <= 2*ys_len).
// Padding states (beyond the sample's label count) have up to 2^100 more
// paths and would drag the scale up until the answer states flush to zero.
// Padding lanes may saturate to inf harmlessly: transitions flow only
// upward (prevB = lane l-1), so they never feed valid lanes, and the
// masked ladder selects 0 (not the value) for them.
// ---------------------------------------------------------------------------
__device__ __forceinline__ float dpp_shr1_zero(float x) {  // lane0 -> 0
    int r = __builtin_amdgcn_update_dpp(0, __float_as_int(x),
                                        0x138 /*wave_shr:1*/, 0xF, 0xF, false);
    return __int_as_float(r);
}
template<int CTRL>
__device__ __forceinline__ float dpp_max_t(float m) {      // ctrl must be literal
    int r = __builtin_amdgcn_update_dpp(0, __float_as_int(m), CTRL, 0xF, 0xF, false);
    return fmaxf(m, __int_as_float(r));
}

#define LOADR(rv, gv, tbase) \
    _Pragma("unroll") \
    for (int u = 0; u < 16; ++u) { \
        int tt = (tbase) + u; tt = tt < TT ? tt : (TT - 1); \
        float raw0 = g[tt * JJ]; \
        float rawB = g[tt * JJ + l + 1]; \
        rv[u] = __builtin_amdgcn_exp2f((rawB - raw0) * LOG2E); \
        gv[u] = (raw0 - ls[tt]) * LOG2E; \
    }

#define RESCALE() { \
        float m_ = fmaxf(fmaxf(vA ? A : 0.f, vB ? B : 0.f), vC ? C : 0.f); \
        m_ = dpp_max_t<0x111>(m_); /* row_shr:1 */ \
        m_ = dpp_max_t<0x112>(m_); /* row_shr:2 */ \
        m_ = dpp_max_t<0x114>(m_); /* row_shr:4 */ \
        m_ = dpp_max_t<0x118>(m_); /* row_shr:8 */ \
        m_ = dpp_max_t<0x142>(m_); /* row_bcast:15 */ \
        m_ = dpp_max_t<0x143>(m_); /* row_bcast:31 */ \
        int mb = __builtin_amdgcn_readlane(__float_as_int(m_), 63); \
        int k_ = ((mb >> 23) & 0xFF) - 127; \
        float sc = __int_as_float((127 - k_) << 23); \
        A *= sc; B *= sc; C *= sc; K += k_; \
    }

#define DOCHUNK(rv, gv, tbase) { \
    const int tb_ = (tbase); \
    if (tb_ + 16 <= Tin) { \
        _Pragma("unroll") \
        for (int u = 0; u < 16; ++u) { \
            float prevB = dpp_shr1_zero(B); \
            float nA = A + prevB; \
            float t1 = A + B; \
            float t2 = skipB ? prevB : 0.f; \
            float nB = (t1 + t2) * rv[u]; \
            float nC = C + B; \
            A = nA; B = nB; C = nC; corr += gv[u]; \
            if (u == 7 || u == 15) RESCALE(); \
        } \
    } else { \
        _Pragma("unroll") \
        for (int u = 0; u < 16; ++u) { \
            bool upd = (tb_ + u) < Tin; \
            float prevB = dpp_shr1_zero(B); \
            float nA = A + prevB; \
            float t1 = A + B; \
            float t2 = skipB ? prevB : 0.f; \
            float nB = (t1 + t2) * rv[u]; \
            float nC = C + B; \
            A = upd ? nA : A; B = upd ? nB : B; C = upd ? nC : C; \
            corr += upd ? gv[u] : 0.f; \
            if (u == 7 || u == 15) RESCALE(); \
        } \
    } }

__global__ __launch_bounds__(64) void ctc_dp(
    const float* __restrict__ glp_raw, const float* __restrict__ lse,
    const int* __restrict__ ys, const int* __restrict__ hs_lens,
    const int* __restrict__ ys_lens, float* __restrict__ nll)
{
    const int b = blockIdx.x;
    const int l = threadIdx.x;          // 0..63; lane l <-> states 2l, 2l+1
    const float* g  = glp_raw + (size_t)b * TT * JJ;
    const float* ls = lse + (size_t)b * TT;
    const int Tin = hs_lens[b];
    const int Ll  = ys_lens[b];         // 32..64

    // valid-state masks (answer reads s = 2Ll and 2Ll-1; states > 2Ll are padding)
    const bool vA = (l <= Ll);                 // A = alpha[2l]
    const bool vB = (l <  Ll);                 // B = alpha[2l+1]
    const bool vC = (l == 63) && (Ll == 64);   // C = alpha[128]

    int cc = ys[b * LL + l];
    bool skipB = false;
    if (l >= 1) { int cp = ys[b * LL + l - 1]; skipB = (cc != 0) && (cc != cp); }

    // t = 0 init (scaled: alpha / p0(0))
    float raw0_0 = g[0];
    float d0 = (g[l + 1] - raw0_0) * LOG2E;
    float A = (l == 0) ? 1.0f : 0.0f;                          // alpha-hat[2l]
    float B = (l == 0) ? __builtin_amdgcn_exp2f(d0) : 0.0f;    // alpha-hat[2l+1]
    float C = 0.0f;                                            // alpha-hat[128] (lane63)
    float corr = (raw0_0 - ls[0]) * LOG2E;                     // sum log2 p0(t)
    int K = 0;                                                 // power-of-2 rescales

    float ra[16], ga_[16], rb[16], gb_[16];
    LOADR(ra, ga_, 1);
    for (int tc = 1; tc < Tin; tc += 32) {
        LOADR(rb, gb_, tc + 16);
        DOCHUNK(ra, ga_, tc);
        LOADR(ra, ga_, tc + 32);
        if (tc + 16 < Tin) DOCHUNK(rb, gb_, tc + 16);
    }

    float v1 = (Ll == 64) ? __shfl(C, 63, 64) : __shfl(A, Ll, 64);  // ah[2Ll]
    float v2 = __shfl(B, Ll - 1, 64);                                // ah[2Ll-1]
    if (l == 0) {
        float ll2 = __builtin_amdgcn_logf(v1 + v2) + (float)K + corr;
        nll[b] = -ll2 * LN2;
    }
}

// ---------------------------------------------------------------------------
// Kernel 6: finalize: out = sum(nll)/B
// ---------------------------------------------------------------------------
__global__ void finalize(const float* __restrict__ nll, float* __restrict__ out)
{
    float v = (threadIdx.x < BB) ? nll[threadIdx.x] : 0.f;
    #pragma unroll
    for (int d = 32; d >= 1; d >>= 1) v += __shfl_down(v, d);
    if (threadIdx.x == 0) out[0] = v / (float)BB;
}

// ---------------------------------------------------------------------------
extern "C" void kernel_launch(void* const* d_in, const int* in_sizes, int n_in,
                              void* d_out, int out_size, void* d_ws, size_t ws_size,
                              hipStream_t stream) {
    const float* hs      = (const float*)d_in[0];   // [16,512,512] f32
    const int*   hs_lens = (const int*)  d_in[1];   // [16]
    const int*   ys      = (const int*)  d_in[2];   // [16,64]
    const int*   ys_lens = (const int*)  d_in[3];   // [16]
    const float* W       = (const float*)d_in[4];   // [512,4096] f32
    const float* bias    = (const float*)d_in[5];   // [4096]
    float* out = (float*)d_out;

    float* ws      = (float*)d_ws;
    float* part    = ws;                                // M*NT64*2 = 1048576 f
    float* lse     = part + (size_t)MM * NT64 * 2;      // 8192 f
    float* glp_raw = lse  + MM;                         // B*T*J = 532480 f
    float* nll     = glp_raw + (size_t)MM * JJ;         // 16 f
    int*   cmap    = (int*)(nll + 16);                  // 1040 i
    bf16*  Abf     = (bf16*)(cmap + 1040);              // 4194304 bf16 (16B-aligned)
    bf16*  Wt      = Abf + (size_t)MM * HH;             // 2097152 bf16

    conv_hs<<<(MM * HH / 4 + 255) / 256, 256, 0, stream>>>(hs, Abf);
    transpose_w<<<dim3(VV / 64, HH / 64), 256, 0, stream>>>(W, Wt);
    make_cmap<<<(BB * JJ + 255) / 256, 256, 0, stream>>>(ys, cmap);
    gemm_lse_mfma<<<dim3(VV / TN, MM / 128), 256, 0, stream>>>(Abf, Wt, bias, cmap, part, glp_raw);
    lse_merge<<<(MM + 255) / 256, 256, 0, stream>>>(part, lse);
    ctc_dp<<<BB, 64, 0, stream>>>(glp_raw, lse, ys, hs_lens, ys_lens, nll);
    finalize<<<1, 64, 0, stream>>>(nll, out);
}

// Round 9
// 199.839 us; speedup vs baseline: 4.3407x; 1.0395x over previous
//
#include <hip/hip_runtime.h>
#include <hip/hip_bf16.h>
#include <math.h>

// Sizes (fixed by the problem)
#define BB   16
#define TT   512
#define HH   512
#define VV   4096
#define LL   64
#define SS   129           // 2*L+1
#define JJ   65            // distinct symbols per sample: blank + L labels
#define MM   (BB*TT)       // 8192 GEMM rows

#define LOG2E 1.4426950408889634f
#define LN2   0.6931471805599453f

typedef __bf16 bf16;
typedef __attribute__((ext_vector_type(4))) __bf16 bf16x4;
typedef __attribute__((ext_vector_type(8))) __bf16 bf16x8;
typedef __attribute__((ext_vector_type(4))) float f32x4;

// ---------------------------------------------------------------------------
// Kernel 0: fused prep. Blocks [0,4096): hs f32 -> Abf bf16.
// Blocks [4096,4608): W [K][N] f32 -> Wt [N][K] bf16 (64x64 LDS transpose).
// ---------------------------------------------------------------------------
__global__ __launch_bounds__(256) void prep(const float* __restrict__ hs,
                                            const float* __restrict__ W,
                                            bf16* __restrict__ Abf,
                                            bf16* __restrict__ Wt)
{
    __shared__ float t[64][65];
    const int tid = threadIdx.x;
    int bx = blockIdx.x;
    if (bx < 4096) {
        int idx = bx * 256 + tid;            // one float4 per thread
        float4 v = ((const float4*)hs)[idx];
        bf16x4 o = {(bf16)v.x, (bf16)v.y, (bf16)v.z, (bf16)v.w};
        *(bf16x4*)(Abf + (size_t)idx * 4) = o;
    } else {
        bx -= 4096;
        const int n0 = (bx & 63) * 64;
        const int k0 = (bx >> 6) * 64;
        #pragma unroll
        for (int i = 0; i < 16; ++i) {
            int idx = tid + i * 256;
            int kk = idx >> 6, nn = idx & 63;
            t[kk][nn] = W[(size_t)(k0 + kk) * VV + n0 + nn];
        }
        __syncthreads();
        #pragma unroll
        for (int i = 0; i < 16; ++i) {
            int idx = tid + i * 256;
            int nl = idx >> 6, kk = idx & 63;
            Wt[(size_t)(n0 + nl) * HH + k0 + kk] = (bf16)t[kk][nl];
        }
    }
}

// ---------------------------------------------------------------------------
// Kernel 1: bf16 MFMA GEMM fused with (a) per-row logsumexp partials and
// (b) scatter of the label-column raw logits (+bias) in TRANSPOSED layout
// glpT[b][j][t] so the DP reads per-lane-contiguous streams.
// ---------------------------------------------------------------------------
#define TN 128
#define NT64 (VV / 64)     // 64 column-tiles of width 64

#define GLDS(src, dst) \
    __builtin_amdgcn_global_load_lds((const __attribute__((address_space(1))) void*)(src), \
                                     (__attribute__((address_space(3))) void*)(dst), 16, 0, 0)

__global__ __launch_bounds__(256) void gemm_lse_mfma(
    const bf16* __restrict__ A,    // [M][512] bf16
    const bf16* __restrict__ Bt,   // [N=4096][512] bf16 (W transposed)
    const float* __restrict__ bias,
    const int*  __restrict__ ys,   // [BB][LL]
    float* __restrict__ part,      // [M][NT64][2] (max, sumexp)
    float* __restrict__ glpT)      // [BB][JJ][TT] raw label logits + bias
{
    __shared__ bf16 As[128 * 32];
    __shared__ bf16 Bs[128 * 32];
    const int tid = threadIdx.x;
    const int lane = tid & 63;
    const int wid = tid >> 6;
    const int wm = wid >> 1, wn = wid & 1;
    const int m0 = blockIdx.y * 128, n0 = blockIdx.x * 128;
    const int lq = lane & 15, kg = lane >> 4;

    f32x4 acc[4][4];
    const f32x4 z = {0.f, 0.f, 0.f, 0.f};
    #pragma unroll
    for (int i = 0; i < 4; ++i)
        #pragma unroll
        for (int j = 0; j < 4; ++j) acc[i][j] = z;

    const int c0 = tid;
    const int row0 = c0 >> 2, sl0 = (c0 & 3) ^ (row0 & 3);
    const int c1 = tid + 256;
    const int row1 = c1 >> 2, sl1 = (c1 & 3) ^ (row1 & 3);
    bf16* dstA0 = As + (size_t)(0 * 256 + (tid & 192)) * 8;
    bf16* dstA1 = As + (size_t)(1 * 256 + (tid & 192)) * 8;
    bf16* dstB0 = Bs + (size_t)(0 * 256 + (tid & 192)) * 8;
    bf16* dstB1 = Bs + (size_t)(1 * 256 + (tid & 192)) * 8;
    const bf16* srcA0 = A  + (size_t)(m0 + row0) * HH + sl0 * 8;
    const bf16* srcA1 = A  + (size_t)(m0 + row1) * HH + sl1 * 8;
    const bf16* srcB0 = Bt + (size_t)(n0 + row0) * HH + sl0 * 8;
    const bf16* srcB1 = Bt + (size_t)(n0 + row1) * HH + sl1 * 8;

    for (int k0 = 0; k0 < HH; k0 += 32) {
        GLDS(srcA0 + k0, dstA0);
        GLDS(srcA1 + k0, dstA1);
        GLDS(srcB0 + k0, dstB0);
        GLDS(srcB1 + k0, dstB1);
        __syncthreads();
        bf16x8 a[4], b[4];
        #pragma unroll
        for (int i = 0; i < 4; ++i) {
            int ar = wm * 64 + i * 16 + lq;
            a[i] = *(const bf16x8*)&As[ar * 32 + ((kg ^ (ar & 3)) * 8)];
        }
        #pragma unroll
        for (int j = 0; j < 4; ++j) {
            int br = wn * 64 + j * 16 + lq;
            b[j] = *(const bf16x8*)&Bs[br * 32 + ((kg ^ (br & 3)) * 8)];
        }
        #pragma unroll
        for (int i = 0; i < 4; ++i)
            #pragma unroll
            for (int j = 0; j < 4; ++j)
                acc[i][j] = __builtin_amdgcn_mfma_f32_16x16x32_bf16(a[i], b[j], acc[i][j], 0, 0, 0);
        __syncthreads();
    }

    // ---- epilogue (a): bias + per-row (this wave's 64-col half) max/sumexp
    const int ct = blockIdx.x * 2 + wn;   // 64-col tile index (race-free)
    float bj[4];
    #pragma unroll
    for (int j = 0; j < 4; ++j) bj[j] = bias[n0 + wn * 64 + j * 16 + lq];
    #pragma unroll
    for (int i = 0; i < 4; ++i) {
        #pragma unroll
        for (int r = 0; r < 4; ++r) {
            float v[4], mx = -3.4e38f;
            #pragma unroll
            for (int j = 0; j < 4; ++j) { v[j] = acc[i][j][r] + bj[j]; mx = fmaxf(mx, v[j]); }
            #pragma unroll
            for (int d = 1; d < 16; d <<= 1) mx = fmaxf(mx, __shfl_xor(mx, d));
            float sm = 0.f;
            #pragma unroll
            for (int j = 0; j < 4; ++j) sm += __expf(v[j] - mx);
            #pragma unroll
            for (int d = 1; d < 16; d <<= 1) sm += __shfl_xor(sm, d);
            if (lq == 0) {
                int rowg = m0 + wm * 64 + i * 16 + kg * 4 + r;
                size_t o = ((size_t)rowg * NT64 + ct) * 2;
                part[o] = mx; part[o + 1] = sm;
            }
        }
    }

    // ---- epilogue (b): scatter label columns -> glpT[b][j][t], float4 stores
    const int bidx = m0 >> 9;               // sample (512 rows per sample)
    const int t0s  = (m0 & 511) + wm * 64;  // base t for this wave
    const int nbase = n0 + wn * 64;
    for (int j = 0; j < JJ; ++j) {
        int c = (j == 0) ? 0 : ys[bidx * LL + j - 1];   // uniform
        int local = c - nbase;
        if (local >= 0 && local < 64) {     // uniform branch (~2 hits/wave)
            int cl = local & 15;
            float bc = bias[c];
            #pragma unroll
            for (int jt = 0; jt < 4; ++jt) {   // static jt: keep acc in regs
                if ((local >> 4) == jt && lq == cl) {
                    float* dst = glpT + ((size_t)(bidx * JJ + j)) * TT + t0s + kg * 4;
                    #pragma unroll
                    for (int i = 0; i < 4; ++i) {
                        f32x4 sv = acc[i][jt];
                        float4 o4 = {sv[0] + bc, sv[1] + bc, sv[2] + bc, sv[3] + bc};
                        *(float4*)(dst + i * 16) = o4;
                    }
                }
            }
        }
    }
}

// ---------------------------------------------------------------------------
// Kernel 2: merge partials -> lse[row]. One wave per row: lane i owns tile i,
// coalesced 512B read per row + shfl reductions.
// ---------------------------------------------------------------------------
__global__ __launch_bounds__(256) void lse_merge(const float* __restrict__ part,
                                                 float* __restrict__ lse)
{
    const int lane = threadIdx.x & 63;
    const int r = blockIdx.x * 4 + (threadIdx.x >> 6);
    const float* p = part + (size_t)r * (NT64 * 2);
    float mx = p[2 * lane];
    float sm = p[2 * lane + 1];
    float wmax = mx;
    #pragma unroll
    for (int d = 1; d < 64; d <<= 1) wmax = fmaxf(wmax, __shfl_xor(wmax, d));
    float c = sm * __expf(mx - wmax);
    #pragma unroll
    for (int d = 1; d < 64; d <<= 1) c += __shfl_xor(c, d);
    if (lane == 0) lse[r] = wmax + logf(c);
}

// ---------------------------------------------------------------------------
// Kernel 3: CTC forward DP, linear domain + exact power-of-2 rescaling
// (valid-state-masked max, r8 fix). Emissions now read from glpT[b][j][t]:
// per chunk of 16 steps, 4x dwordx4 per-lane + 4x dwordx4 uniform (blank row).
// lse enters only as a per-sample scalar sum, computed once at the end.
// ---------------------------------------------------------------------------
__device__ __forceinline__ float dpp_shr1_zero(float x) {  // lane0 -> 0
    int r = __builtin_amdgcn_update_dpp(0, __float_as_int(x),
                                        0x138 /*wave_shr:1*/, 0xF, 0xF, false);
    return __int_as_float(r);
}
template<int CTRL>
__device__ __forceinline__ float dpp_max_t(float m) {      // ctrl must be literal
    int r = __builtin_amdgcn_update_dpp(0, __float_as_int(m), CTRL, 0xF, 0xF, false);
    return fmaxf(m, __int_as_float(r));
}

#define LOADA(rv, gv, blk) { \
    int bb_ = (blk); bb_ = bb_ < 32 ? bb_ : 31; \
    const float4* p0_ = (const float4*)(g0 + bb_ * 16); \
    const float4* pB_ = (const float4*)(gB + bb_ * 16); \
    float4 q0_[4], qB_[4]; \
    q0_[0] = p0_[0]; q0_[1] = p0_[1]; q0_[2] = p0_[2]; q0_[3] = p0_[3]; \
    qB_[0] = pB_[0]; qB_[1] = pB_[1]; qB_[2] = pB_[2]; qB_[3] = pB_[3]; \
    _Pragma("unroll") \
    for (int u = 0; u < 16; ++u) { \
        float raw0_ = ((const float*)q0_)[u]; \
        float rawB_ = ((const float*)qB_)[u]; \
        rv[u] = __builtin_amdgcn_exp2f((rawB_ - raw0_) * LOG2E); \
        gv[u] = raw0_; \
    } }

#define RESCALE() { \
        float m_ = fmaxf(fmaxf(vA ? A : 0.f, vB ? B : 0.f), vC ? C : 0.f); \
        m_ = dpp_max_t<0x111>(m_); /* row_shr:1 */ \
        m_ = dpp_max_t<0x112>(m_); /* row_shr:2 */ \
        m_ = dpp_max_t<0x114>(m_); /* row_shr:4 */ \
        m_ = dpp_max_t<0x118>(m_); /* row_shr:8 */ \
        m_ = dpp_max_t<0x142>(m_); /* row_bcast:15 */ \
        m_ = dpp_max_t<0x143>(m_); /* row_bcast:31 */ \
        int mb = __builtin_amdgcn_readlane(__float_as_int(m_), 63); \
        int k_ = ((mb >> 23) & 0xFF) - 127; \
        float sc = __int_as_float((127 - k_) << 23); \
        A *= sc; B *= sc; C *= sc; K += k_; \
    }

#define DO16(rv, gv, blk, SKIP0) { \
    const int tB_ = (blk) * 16; \
    if (!(SKIP0) && tB_ + 16 <= Tin) { \
        _Pragma("unroll") \
        for (int u = 0; u < 16; ++u) { \
            float prevB = dpp_shr1_zero(B); \
            float nA = A + prevB; \
            float t1 = A + B; \
            float t2 = skipB ? prevB : 0.f; \
            float nB = (t1 + t2) * rv[u]; \
            float nC = C + B; \
            A = nA; B = nB; C = nC; corr += gv[u]; \
            if (u == 7 || u == 15) RESCALE(); \
        } \
    } else { \
        _Pragma("unroll") \
        for (int u = 0; u < 16; ++u) { \
            int t_ = tB_ + u; \
            bool upd = (t_ >= 1) && (t_ < Tin); \
            float prevB = dpp_shr1_zero(B); \
            float nA = A + prevB; \
            float t1 = A + B; \
            float t2 = skipB ? prevB : 0.f; \
            float nB = (t1 + t2) * rv[u]; \
            float nC = C + B; \
            A = upd ? nA : A; B = upd ? nB : B; C = upd ? nC : C; \
            corr += upd ? gv[u] : 0.f; \
            if (u == 7 || u == 15) RESCALE(); \
        } \
    } }

__global__ __launch_bounds__(64) void ctc_dp(
    const float* __restrict__ glpT, const float* __restrict__ lse,
    const int* __restrict__ ys, const int* __restrict__ hs_lens,
    const int* __restrict__ ys_lens, float* __restrict__ nll)
{
    const int b = blockIdx.x;
    const int l = threadIdx.x;          // 0..63; lane l <-> states 2l, 2l+1
    const float* g0 = glpT + (size_t)(b * JJ) * TT;            // blank row
    const float* gB = glpT + (size_t)(b * JJ + l + 1) * TT;    // this lane's label row
    const float* ls = lse + (size_t)b * TT;
    const int Tin = hs_lens[b];
    const int Ll  = ys_lens[b];         // 32..64

    // valid-state masks (answer reads s = 2Ll and 2Ll-1; states > 2Ll are padding)
    const bool vA = (l <= Ll);                 // A = alpha[2l]
    const bool vB = (l <  Ll);                 // B = alpha[2l+1]
    const bool vC = (l == 63) && (Ll == 64);   // C = alpha[128]

    int cc = ys[b * LL + l];
    bool skipB = false;
    if (l >= 1) { int cp = ys[b * LL + l - 1]; skipB = (cc != 0) && (cc != cp); }

    // t = 0 init (scaled: alpha / p0(0))
    float raw0_0 = g0[0];
    float d0 = (gB[0] - raw0_0) * LOG2E;
    float A = (l == 0) ? 1.0f : 0.0f;                          // alpha-hat[2l]
    float B = (l == 0) ? __builtin_amdgcn_exp2f(d0) : 0.0f;    // alpha-hat[2l+1]
    float C = 0.0f;                                            // alpha-hat[128] (lane63)
    float corr = raw0_0;                                       // sum of raw0 (t<Tin)
    int K = 0;                                                 // power-of-2 rescales

    float ra[16], ga[16], rb[16], gb[16];
    LOADA(ra, ga, 0);
    // NOTE: corr must not double-count t=0 -> first block skips u=0 (SKIP0),
    // and its gv[0] is not accumulated in the masked path (upd false at t=0).
    for (int blk = 0; blk < 32; blk += 2) {
        LOADA(rb, gb, blk + 1);
        DO16(ra, ga, blk, (blk == 0));
        LOADA(ra, ga, blk + 2);
        DO16(rb, gb, blk + 1, false);
        if (16 * (blk + 2) >= Tin) break;
    }

    // per-sample sum of lse over t < Tin (lane-parallel + wave reduce)
    float lsum = 0.f;
    for (int tt = l; tt < Tin; tt += 64) lsum += ls[tt];
    #pragma unroll
    for (int d = 1; d < 64; d <<= 1) lsum += __shfl_xor(lsum, d);

    float v1 = (Ll == 64) ? __shfl(C, 63, 64) : __shfl(A, Ll, 64);  // ah[2Ll]
    float v2 = __shfl(B, Ll - 1, 64);                                // ah[2Ll-1]
    if (l == 0) {
        float ll2 = __builtin_amdgcn_logf(v1 + v2) + (float)K + (corr - lsum) * LOG2E;
        nll[b] = -ll2 * LN2;
    }
}

// ---------------------------------------------------------------------------
// Kernel 4: finalize: out = sum(nll)/B
// ---------------------------------------------------------------------------
__global__ void finalize(const float* __restrict__ nll, float* __restrict__ out)
{
    float v = (threadIdx.x < BB) ? nll[threadIdx.x] : 0.f;
    #pragma unroll
    for (int d = 32; d >= 1; d >>= 1) v += __shfl_down(v, d);
    if (threadIdx.x == 0) out[0] = v / (float)BB;
}

// ---------------------------------------------------------------------------
extern "C" void kernel_launch(void* const* d_in, const int* in_sizes, int n_in,
                              void* d_out, int out_size, void* d_ws, size_t ws_size,
                              hipStream_t stream) {
    const float* hs      = (const float*)d_in[0];   // [16,512,512] f32
    const int*   hs_lens = (const int*)  d_in[1];   // [16]
    const int*   ys      = (const int*)  d_in[2];   // [16,64]
    const int*   ys_lens = (const int*)  d_in[3];   // [16]
    const float* W       = (const float*)d_in[4];   // [512,4096] f32
    const float* bias    = (const float*)d_in[5];   // [4096]
    float* out = (float*)d_out;

    float* ws   = (float*)d_ws;
    float* part = ws;                                // M*NT64*2 = 1048576 f
    float* lse  = part + (size_t)MM * NT64 * 2;      // 8192 f
    float* glpT = lse  + MM;                         // B*J*T = 532480 f
    float* nll  = glpT + (size_t)BB * JJ * TT;       // 16 f
    bf16*  Abf  = (bf16*)(nll + 16);                 // 4194304 bf16 (16B-aligned)
    bf16*  Wt   = Abf + (size_t)MM * HH;             // 2097152 bf16

    prep<<<4608, 256, 0, stream>>>(hs, W, Abf, Wt);
    gemm_lse_mfma<<<dim3(VV / TN, MM / 128), 256, 0, stream>>>(Abf, Wt, bias, ys, part, glpT);
    lse_merge<<<MM / 4, 256, 0, stream>>>(part, lse);
    ctc_dp<<<BB, 64, 0, stream>>>(glpT, lse, ys, hs_lens, ys_lens, nll);
    finalize<<<1, 64, 0, stream>>>(nll, out);
}

// Round 10
// 187.299 us; speedup vs baseline: 4.6313x; 1.0670x over previous
//
#include <hip/hip_runtime.h>
#include <hip/hip_bf16.h>
#include <math.h>

// Sizes (fixed by the problem)
#define BB   16
#define TT   512
#define HH   512
#define VV   4096
#define LL   64
#define SS   129           // 2*L+1
#define JJ   65            // distinct symbols per sample: blank + L labels
#define MM   (BB*TT)       // 8192 GEMM rows

#define LOG2E 1.4426950408889634f
#define LN2   0.6931471805599453f

typedef __bf16 bf16;
typedef __attribute__((ext_vector_type(4))) __bf16 bf16x4;
typedef __attribute__((ext_vector_type(8))) __bf16 bf16x8;
typedef __attribute__((ext_vector_type(4))) float f32x4;

// DPP helpers ---------------------------------------------------------------
template<int CTRL>
__device__ __forceinline__ float dpp_mov(float x) {   // moved value (all lanes valid)
    return __int_as_float(__builtin_amdgcn_update_dpp(
        __float_as_int(x), __float_as_int(x), CTRL, 0xF, 0xF, false));
}
// reduce across the 16-lane DPP row via rotations (commutative op)
__device__ __forceinline__ float row16_max(float x) {
    x = fmaxf(x, dpp_mov<0x128>(x));  // row_ror:8
    x = fmaxf(x, dpp_mov<0x124>(x));  // row_ror:4
    x = fmaxf(x, dpp_mov<0x122>(x));  // row_ror:2
    x = fmaxf(x, dpp_mov<0x121>(x));  // row_ror:1
    return x;                          // full 16-lane max in every lane
}
__device__ __forceinline__ float row16_sum(float x) {
    x += dpp_mov<0x128>(x);
    x += dpp_mov<0x124>(x);
    x += dpp_mov<0x122>(x);
    x += dpp_mov<0x121>(x);
    return x;
}
__device__ __forceinline__ float dpp_shr1_zero(float x) {  // wave shift; lane0 -> 0
    int r = __builtin_amdgcn_update_dpp(0, __float_as_int(x),
                                        0x138 /*wave_shr:1*/, 0xF, 0xF, false);
    return __int_as_float(r);
}
template<int CTRL>
__device__ __forceinline__ float dpp_max_t(float m) {
    int r = __builtin_amdgcn_update_dpp(0, __float_as_int(m), CTRL, 0xF, 0xF, false);
    return fmaxf(m, __int_as_float(r));
}

// ---------------------------------------------------------------------------
// Kernel 0: fused prep. Blocks [0,4096): hs f32 -> Abf bf16.
// Blocks [4096,4608): W [K][N] f32 -> Wt [N][K] bf16 (64x64 LDS transpose).
// ---------------------------------------------------------------------------
__global__ __launch_bounds__(256) void prep(const float* __restrict__ hs,
                                            const float* __restrict__ W,
                                            bf16* __restrict__ Abf,
                                            bf16* __restrict__ Wt)
{
    __shared__ float t[64][65];
    const int tid = threadIdx.x;
    int bx = blockIdx.x;
    if (bx < 4096) {
        int idx = bx * 256 + tid;            // one float4 per thread
        float4 v = ((const float4*)hs)[idx];
        bf16x4 o = {(bf16)v.x, (bf16)v.y, (bf16)v.z, (bf16)v.w};
        *(bf16x4*)(Abf + (size_t)idx * 4) = o;
    } else {
        bx -= 4096;
        const int n0 = (bx & 63) * 64;
        const int k0 = (bx >> 6) * 64;
        #pragma unroll
        for (int i = 0; i < 16; ++i) {
            int idx = tid + i * 256;
            int kk = idx >> 6, nn = idx & 63;
            t[kk][nn] = W[(size_t)(k0 + kk) * VV + n0 + nn];
        }
        __syncthreads();
        #pragma unroll
        for (int i = 0; i < 16; ++i) {
            int idx = tid + i * 256;
            int nl = idx >> 6, kk = idx & 63;
            Wt[(size_t)(n0 + nl) * HH + k0 + kk] = (bf16)t[kk][nl];
        }
    }
}

// ---------------------------------------------------------------------------
// Kernel 1: bf16 MFMA GEMM fused with (a) per-row logsumexp partials (DPP
// row-reductions) and (b) scalar-store scatter of label columns -> glpT[b][j][t].
// ---------------------------------------------------------------------------
#define TN 128
#define NT64 (VV / 64)     // 64 column-tiles of width 64

#define GLDS(src, dst) \
    __builtin_amdgcn_global_load_lds((const __attribute__((address_space(1))) void*)(src), \
                                     (__attribute__((address_space(3))) void*)(dst), 16, 0, 0)

__global__ __launch_bounds__(256) void gemm_lse_mfma(
    const bf16* __restrict__ A,    // [M][512] bf16
    const bf16* __restrict__ Bt,   // [N=4096][512] bf16 (W transposed)
    const float* __restrict__ bias,
    const int*  __restrict__ ys,   // [BB][LL]
    float* __restrict__ part,      // [M][NT64][2] (max, sumexp)
    float* __restrict__ glpT)      // [BB][JJ][TT] raw label logits + bias
{
    __shared__ bf16 As[128 * 32];
    __shared__ bf16 Bs[128 * 32];
    const int tid = threadIdx.x;
    const int lane = tid & 63;
    const int wid = tid >> 6;
    const int wm = wid >> 1, wn = wid & 1;
    const int m0 = blockIdx.y * 128, n0 = blockIdx.x * 128;
    const int lq = lane & 15, kg = lane >> 4;

    f32x4 acc[4][4];
    const f32x4 z = {0.f, 0.f, 0.f, 0.f};
    #pragma unroll
    for (int i = 0; i < 4; ++i)
        #pragma unroll
        for (int j = 0; j < 4; ++j) acc[i][j] = z;

    const int c0 = tid;
    const int row0 = c0 >> 2, sl0 = (c0 & 3) ^ (row0 & 3);
    const int c1 = tid + 256;
    const int row1 = c1 >> 2, sl1 = (c1 & 3) ^ (row1 & 3);
    bf16* dstA0 = As + (size_t)(0 * 256 + (tid & 192)) * 8;
    bf16* dstA1 = As + (size_t)(1 * 256 + (tid & 192)) * 8;
    bf16* dstB0 = Bs + (size_t)(0 * 256 + (tid & 192)) * 8;
    bf16* dstB1 = Bs + (size_t)(1 * 256 + (tid & 192)) * 8;
    const bf16* srcA0 = A  + (size_t)(m0 + row0) * HH + sl0 * 8;
    const bf16* srcA1 = A  + (size_t)(m0 + row1) * HH + sl1 * 8;
    const bf16* srcB0 = Bt + (size_t)(n0 + row0) * HH + sl0 * 8;
    const bf16* srcB1 = Bt + (size_t)(n0 + row1) * HH + sl1 * 8;

    for (int k0 = 0; k0 < HH; k0 += 32) {
        GLDS(srcA0 + k0, dstA0);
        GLDS(srcA1 + k0, dstA1);
        GLDS(srcB0 + k0, dstB0);
        GLDS(srcB1 + k0, dstB1);
        __syncthreads();
        bf16x8 a[4], b[4];
        #pragma unroll
        for (int i = 0; i < 4; ++i) {
            int ar = wm * 64 + i * 16 + lq;
            a[i] = *(const bf16x8*)&As[ar * 32 + ((kg ^ (ar & 3)) * 8)];
        }
        #pragma unroll
        for (int j = 0; j < 4; ++j) {
            int br = wn * 64 + j * 16 + lq;
            b[j] = *(const bf16x8*)&Bs[br * 32 + ((kg ^ (br & 3)) * 8)];
        }
        #pragma unroll
        for (int i = 0; i < 4; ++i)
            #pragma unroll
            for (int j = 0; j < 4; ++j)
                acc[i][j] = __builtin_amdgcn_mfma_f32_16x16x32_bf16(a[i], b[j], acc[i][j], 0, 0, 0);
        __syncthreads();
    }

    // ---- epilogue (a): bias + per-row (this wave's 64-col half) max/sumexp
    // DPP row_ror reductions across the 16-lane group (no LDS shuffles).
    const int ct = blockIdx.x * 2 + wn;   // 64-col tile index (race-free)
    float bj[4];
    #pragma unroll
    for (int j = 0; j < 4; ++j) bj[j] = bias[n0 + wn * 64 + j * 16 + lq];
    #pragma unroll
    for (int i = 0; i < 4; ++i) {
        #pragma unroll
        for (int r = 0; r < 4; ++r) {
            float v[4], mx = -3.4e38f;
            #pragma unroll
            for (int j = 0; j < 4; ++j) { v[j] = acc[i][j][r] + bj[j]; mx = fmaxf(mx, v[j]); }
            mx = row16_max(mx);
            float sm = 0.f;
            #pragma unroll
            for (int j = 0; j < 4; ++j) sm += __expf(v[j] - mx);
            sm = row16_sum(sm);
            if (lq == 0) {
                int rowg = m0 + wm * 64 + i * 16 + kg * 4 + r;
                size_t o = ((size_t)rowg * NT64 + ct) * 2;
                part[o] = mx; part[o + 1] = sm;
            }
        }
    }

    // ---- epilogue (b): scatter label columns -> glpT[b][j][t] (scalar stores)
    const int bidx = m0 >> 9;               // sample (512 rows per sample)
    const int t0s  = (m0 & 511) + wm * 64;  // base t for this wave
    const int nbase = n0 + wn * 64;
    for (int j = 0; j < JJ; ++j) {
        int c = (j == 0) ? 0 : ys[bidx * LL + j - 1];   // uniform
        int local = c - nbase;
        if (local >= 0 && local < 64) {     // uniform branch (~2 hits/wave)
            int cl = local & 15;
            float bc = bias[c];
            #pragma unroll
            for (int jt = 0; jt < 4; ++jt) {   // static jt: keep acc in regs
                if ((local >> 4) == jt && lq == cl) {
                    #pragma unroll
                    for (int i = 0; i < 4; ++i)
                        #pragma unroll
                        for (int r = 0; r < 4; ++r) {
                            int tt = t0s + i * 16 + kg * 4 + r;
                            glpT[(size_t)(bidx * JJ + j) * TT + tt] = acc[i][jt][r] + bc;
                        }
                }
            }
        }
    }
}

// ---------------------------------------------------------------------------
// Kernel 2: merge partials -> lse[row]. One wave per row, coalesced.
// ---------------------------------------------------------------------------
__global__ __launch_bounds__(256) void lse_merge(const float* __restrict__ part,
                                                 float* __restrict__ lse)
{
    const int lane = threadIdx.x & 63;
    const int r = blockIdx.x * 4 + (threadIdx.x >> 6);
    const float* p = part + (size_t)r * (NT64 * 2);
    float mx = p[2 * lane];
    float sm = p[2 * lane + 1];
    float wmax = mx;
    #pragma unroll
    for (int d = 1; d < 64; d <<= 1) wmax = fmaxf(wmax, __shfl_xor(wmax, d));
    float c = sm * __expf(mx - wmax);
    #pragma unroll
    for (int d = 1; d < 64; d <<= 1) c += __shfl_xor(c, d);
    if (lane == 0) lse[r] = wmax + logf(c);
}

// ---------------------------------------------------------------------------
// Kernel 3: CTC forward DP, linear domain + exact power-of-2 rescaling
// (valid-state-masked max). Software-pipelined: raw emission chunks loaded
// into float4 register buffers 2 chunks ahead; exp2 happens at consume time.
// ---------------------------------------------------------------------------
#define F4AT(arr, u) ( ((u) & 3) == 0 ? arr[(u) >> 2].x \
                     : ((u) & 3) == 1 ? arr[(u) >> 2].y \
                     : ((u) & 3) == 2 ? arr[(u) >> 2].z : arr[(u) >> 2].w )

#define LOADI(p0v, pBv, blk) { \
    int bb_ = (blk); bb_ = bb_ < 32 ? bb_ : 31; \
    const float4* p0_ = (const float4*)(g0 + bb_ * 16); \
    const float4* pB_ = (const float4*)(gB + bb_ * 16); \
    p0v[0] = p0_[0]; p0v[1] = p0_[1]; p0v[2] = p0_[2]; p0v[3] = p0_[3]; \
    pBv[0] = pB_[0]; pBv[1] = pB_[1]; pBv[2] = pB_[2]; pBv[3] = pB_[3]; \
}

// exp2 of ratios + corr chunk-sum (all off the DP dependency chain)
#define RVCOMP(rv, p0v, pBv, blk) { \
    const int tB_ = (blk) * 16; \
    _Pragma("unroll") \
    for (int u = 0; u < 16; ++u) { \
        rv[u] = __builtin_amdgcn_exp2f((F4AT(pBv, u) - F4AT(p0v, u)) * LOG2E); \
    } \
    if (tB_ > 0 && tB_ + 16 <= Tin) { \
        float s_ = 0.f; \
        _Pragma("unroll") \
        for (int u = 0; u < 16; ++u) s_ += F4AT(p0v, u); \
        corr += s_; \
    } else { \
        float s_ = 0.f; \
        _Pragma("unroll") \
        for (int u = 0; u < 16; ++u) { \
            int t_ = tB_ + u; \
            s_ += (t_ >= 1 && t_ < Tin) ? F4AT(p0v, u) : 0.f; \
        } \
        corr += s_; \
    } }

#define RESCALE() { \
        float m_ = fmaxf(fmaxf(vA ? A : 0.f, vB ? B : 0.f), vC ? C : 0.f); \
        m_ = dpp_max_t<0x111>(m_); /* row_shr:1 */ \
        m_ = dpp_max_t<0x112>(m_); /* row_shr:2 */ \
        m_ = dpp_max_t<0x114>(m_); /* row_shr:4 */ \
        m_ = dpp_max_t<0x118>(m_); /* row_shr:8 */ \
        m_ = dpp_max_t<0x142>(m_); /* row_bcast:15 */ \
        m_ = dpp_max_t<0x143>(m_); /* row_bcast:31 */ \
        int mb = __builtin_amdgcn_readlane(__float_as_int(m_), 63); \
        int k_ = ((mb >> 23) & 0xFF) - 127; \
        float sc = __int_as_float((127 - k_) << 23); \
        A *= sc; B *= sc; C *= sc; K += k_; \
    }

#define DO16N(rv, blk) { \
    const int tB_ = (blk) * 16; \
    if (tB_ > 0 && tB_ + 16 <= Tin) { \
        _Pragma("unroll") \
        for (int u = 0; u < 16; ++u) { \
            float prevB = dpp_shr1_zero(B); \
            float nA = A + prevB; \
            float t1 = A + B; \
            float t2 = skipB ? prevB : 0.f; \
            float nB = (t1 + t2) * rv[u]; \
            float nC = C + B; \
            A = nA; B = nB; C = nC; \
            if (u == 7 || u == 15) RESCALE(); \
        } \
    } else { \
        _Pragma("unroll") \
        for (int u = 0; u < 16; ++u) { \
            int t_ = tB_ + u; \
            bool upd = (t_ >= 1) && (t_ < Tin); \
            float prevB = dpp_shr1_zero(B); \
            float nA = A + prevB; \
            float t1 = A + B; \
            float t2 = skipB ? prevB : 0.f; \
            float nB = (t1 + t2) * rv[u]; \
            float nC = C + B; \
            A = upd ? nA : A; B = upd ? nB : B; C = upd ? nC : C; \
            if (u == 7 || u == 15) RESCALE(); \
        } \
    } }

__global__ __launch_bounds__(64) void ctc_dp(
    const float* __restrict__ glpT, const float* __restrict__ lse,
    const int* __restrict__ ys, const int* __restrict__ hs_lens,
    const int* __restrict__ ys_lens, float* __restrict__ nll)
{
    const int b = blockIdx.x;
    const int l = threadIdx.x;          // 0..63; lane l <-> states 2l, 2l+1
    const float* g0 = glpT + (size_t)(b * JJ) * TT;            // blank row
    const float* gB = glpT + (size_t)(b * JJ + l + 1) * TT;    // this lane's label row
    const float* ls = lse + (size_t)b * TT;
    const int Tin = hs_lens[b];
    const int Ll  = ys_lens[b];         // 32..64

    // valid-state masks (answer reads s = 2Ll and 2Ll-1; states > 2Ll are padding)
    const bool vA = (l <= Ll);                 // A = alpha[2l]
    const bool vB = (l <  Ll);                 // B = alpha[2l+1]
    const bool vC = (l == 63) && (Ll == 64);   // C = alpha[128]

    int cc = ys[b * LL + l];
    bool skipB = false;
    if (l >= 1) { int cp = ys[b * LL + l - 1]; skipB = (cc != 0) && (cc != cp); }

    // t = 0 init (scaled: alpha / p0(0))
    float raw0_0 = g0[0];
    float d0 = (gB[0] - raw0_0) * LOG2E;
    float A = (l == 0) ? 1.0f : 0.0f;                          // alpha-hat[2l]
    float B = (l == 0) ? __builtin_amdgcn_exp2f(d0) : 0.0f;    // alpha-hat[2l+1]
    float C = 0.0f;                                            // alpha-hat[128] (lane63)
    float corr = raw0_0;                                       // sum of raw0 (t<Tin)
    int K = 0;                                                 // power-of-2 rescales

    float4 p0a[4], pBa[4], p0b[4], pBb[4];
    float rva[16], rvb[16];
    LOADI(p0a, pBa, 0);
    LOADI(p0b, pBb, 1);
    for (int blk = 0; blk < 32; blk += 2) {
        RVCOMP(rva, p0a, pBa, blk);        // waits loads issued 1 iter ago
        LOADI(p0a, pBa, blk + 2);          // prefetch 2 chunks ahead
        DO16N(rva, blk);
        RVCOMP(rvb, p0b, pBb, blk + 1);
        LOADI(p0b, pBb, blk + 3);
        DO16N(rvb, blk + 1);
        if (16 * (blk + 2) >= Tin) break;
    }

    // per-sample sum of lse over t < Tin (lane-parallel + wave reduce)
    float lsum = 0.f;
    for (int tt = l; tt < Tin; tt += 64) lsum += ls[tt];
    #pragma unroll
    for (int d = 1; d < 64; d <<= 1) lsum += __shfl_xor(lsum, d);

    float v1 = (Ll == 64) ? __shfl(C, 63, 64) : __shfl(A, Ll, 64);  // ah[2Ll]
    float v2 = __shfl(B, Ll - 1, 64);                                // ah[2Ll-1]
    if (l == 0) {
        float ll2 = __builtin_amdgcn_logf(v1 + v2) + (float)K + (corr - lsum) * LOG2E;
        nll[b] = -ll2 * LN2;
    }
}

// ---------------------------------------------------------------------------
// Kernel 4: finalize: out = sum(nll)/B
// ---------------------------------------------------------------------------
__global__ void finalize(const float* __restrict__ nll, float* __restrict__ out)
{
    float v = (threadIdx.x < BB) ? nll[threadIdx.x] : 0.f;
    #pragma unroll
    for (int d = 32; d >= 1; d >>= 1) v += __shfl_down(v, d);
    if (threadIdx.x == 0) out[0] = v / (float)BB;
}

// ---------------------------------------------------------------------------
extern "C" void kernel_launch(void* const* d_in, const int* in_sizes, int n_in,
                              void* d_out, int out_size, void* d_ws, size_t ws_size,
                              hipStream_t stream) {
    const float* hs      = (const float*)d_in[0];   // [16,512,512] f32
    const int*   hs_lens = (const int*)  d_in[1];   // [16]
    const int*   ys      = (const int*)  d_in[2];   // [16,64]
    const int*   ys_lens = (const int*)  d_in[3];   // [16]
    const float* W       = (const float*)d_in[4];   // [512,4096] f32
    const float* bias    = (const float*)d_in[5];   // [4096]
    float* out = (float*)d_out;

    float* ws   = (float*)d_ws;
    float* part = ws;                                // M*NT64*2 = 1048576 f
    float* lse  = part + (size_t)MM * NT64 * 2;      // 8192 f
    float* glpT = lse  + MM;                         // B*J*T = 532480 f
    float* nll  = glpT + (size_t)BB * JJ * TT;       // 16 f
    bf16*  Abf  = (bf16*)(nll + 16);                 // 4194304 bf16 (16B-aligned)
    bf16*  Wt   = Abf + (size_t)MM * HH;             // 2097152 bf16

    prep<<<4608, 256, 0, stream>>>(hs, W, Abf, Wt);
    gemm_lse_mfma<<<dim3(VV / TN, MM / 128), 256, 0, stream>>>(Abf, Wt, bias, ys, part, glpT);
    lse_merge<<<MM / 4, 256, 0, stream>>>(part, lse);
    ctc_dp<<<BB, 64, 0, stream>>>(glpT, lse, ys, hs_lens, ys_lens, nll);
    finalize<<<1, 64, 0, stream>>>(nll, out);
}

// Round 11
// 183.222 us; speedup vs baseline: 4.7344x; 1.0222x over previous
//
#include <hip/hip_runtime.h>
#include <hip/hip_bf16.h>
#include <math.h>

// Sizes (fixed by the problem)
#define BB   16
#define TT   512
#define HH   512
#define VV   4096
#define LL   64
#define SS   129           // 2*L+1
#define JJ   65            // distinct symbols per sample: blank + L labels
#define MM   (BB*TT)       // 8192 GEMM rows

#define LOG2E 1.4426950408889634f
#define LN2   0.6931471805599453f

typedef __bf16 bf16;
typedef __attribute__((ext_vector_type(4))) __bf16 bf16x4;
typedef __attribute__((ext_vector_type(8))) __bf16 bf16x8;
typedef __attribute__((ext_vector_type(4))) float f32x4;

// DPP helpers ---------------------------------------------------------------
template<int CTRL>
__device__ __forceinline__ float dpp_mov(float x) {   // moved value (all lanes valid)
    return __int_as_float(__builtin_amdgcn_update_dpp(
        __float_as_int(x), __float_as_int(x), CTRL, 0xF, 0xF, false));
}
__device__ __forceinline__ float row16_max(float x) {
    x = fmaxf(x, dpp_mov<0x128>(x));  // row_ror:8
    x = fmaxf(x, dpp_mov<0x124>(x));  // row_ror:4
    x = fmaxf(x, dpp_mov<0x122>(x));  // row_ror:2
    x = fmaxf(x, dpp_mov<0x121>(x));  // row_ror:1
    return x;
}
__device__ __forceinline__ float row16_sum(float x) {
    x += dpp_mov<0x128>(x);
    x += dpp_mov<0x124>(x);
    x += dpp_mov<0x122>(x);
    x += dpp_mov<0x121>(x);
    return x;
}
__device__ __forceinline__ float dpp_shr1_zero(float x) {  // wave shift; lane0 -> 0
    int r = __builtin_amdgcn_update_dpp(0, __float_as_int(x),
                                        0x138 /*wave_shr:1*/, 0xF, 0xF, false);
    return __int_as_float(r);
}
template<int CTRL>
__device__ __forceinline__ float dpp_max_t(float m) {
    int r = __builtin_amdgcn_update_dpp(0, __float_as_int(m), CTRL, 0xF, 0xF, false);
    return fmaxf(m, __int_as_float(r));
}

// ---------------------------------------------------------------------------
// Kernel 0: fused prep. Blocks [0,4096): hs f32 -> Abf bf16.
// Blocks [4096,4608): W [K][N] f32 -> Wt [N][K] bf16 (64x64 LDS transpose).
// Block 0 thread 0 also zeroes out[0] (stream-ordered before ctc_tail's atomics).
// ---------------------------------------------------------------------------
__global__ __launch_bounds__(256) void prep(const float* __restrict__ hs,
                                            const float* __restrict__ W,
                                            bf16* __restrict__ Abf,
                                            bf16* __restrict__ Wt,
                                            float* __restrict__ out)
{
    __shared__ float t[64][65];
    const int tid = threadIdx.x;
    int bx = blockIdx.x;
    if (bx == 0 && tid == 0) out[0] = 0.f;
    if (bx < 4096) {
        int idx = bx * 256 + tid;            // one float4 per thread
        float4 v = ((const float4*)hs)[idx];
        bf16x4 o = {(bf16)v.x, (bf16)v.y, (bf16)v.z, (bf16)v.w};
        *(bf16x4*)(Abf + (size_t)idx * 4) = o;
    } else {
        bx -= 4096;
        const int n0 = (bx & 63) * 64;
        const int k0 = (bx >> 6) * 64;
        #pragma unroll
        for (int i = 0; i < 16; ++i) {
            int idx = tid + i * 256;
            int kk = idx >> 6, nn = idx & 63;
            t[kk][nn] = W[(size_t)(k0 + kk) * VV + n0 + nn];
        }
        __syncthreads();
        #pragma unroll
        for (int i = 0; i < 16; ++i) {
            int idx = tid + i * 256;
            int nl = idx >> 6, kk = idx & 63;
            Wt[(size_t)(n0 + nl) * HH + k0 + kk] = (bf16)t[kk][nl];
        }
    }
}

// ---------------------------------------------------------------------------
// Kernel 1: bf16 MFMA GEMM fused with (a) per-row logsumexp partials (DPP
// row-reductions) and (b) scalar-store scatter of label columns -> glpT[b][j][t].
// (unchanged from r10 — verified)
// ---------------------------------------------------------------------------
#define TN 128
#define NT64 (VV / 64)     // 64 column-tiles of width 64

#define GLDS(src, dst) \
    __builtin_amdgcn_global_load_lds((const __attribute__((address_space(1))) void*)(src), \
                                     (__attribute__((address_space(3))) void*)(dst), 16, 0, 0)

__global__ __launch_bounds__(256) void gemm_lse_mfma(
    const bf16* __restrict__ A,    // [M][512] bf16
    const bf16* __restrict__ Bt,   // [N=4096][512] bf16 (W transposed)
    const float* __restrict__ bias,
    const int*  __restrict__ ys,   // [BB][LL]
    float* __restrict__ part,      // [M][NT64][2] (max, sumexp)
    float* __restrict__ glpT)      // [BB][JJ][TT] raw label logits + bias
{
    __shared__ bf16 As[128 * 32];
    __shared__ bf16 Bs[128 * 32];
    const int tid = threadIdx.x;
    const int lane = tid & 63;
    const int wid = tid >> 6;
    const int wm = wid >> 1, wn = wid & 1;
    const int m0 = blockIdx.y * 128, n0 = blockIdx.x * 128;
    const int lq = lane & 15, kg = lane >> 4;

    f32x4 acc[4][4];
    const f32x4 z = {0.f, 0.f, 0.f, 0.f};
    #pragma unroll
    for (int i = 0; i < 4; ++i)
        #pragma unroll
        for (int j = 0; j < 4; ++j) acc[i][j] = z;

    const int c0 = tid;
    const int row0 = c0 >> 2, sl0 = (c0 & 3) ^ (row0 & 3);
    const int c1 = tid + 256;
    const int row1 = c1 >> 2, sl1 = (c1 & 3) ^ (row1 & 3);
    bf16* dstA0 = As + (size_t)(0 * 256 + (tid & 192)) * 8;
    bf16* dstA1 = As + (size_t)(1 * 256 + (tid & 192)) * 8;
    bf16* dstB0 = Bs + (size_t)(0 * 256 + (tid & 192)) * 8;
    bf16* dstB1 = Bs + (size_t)(1 * 256 + (tid & 192)) * 8;
    const bf16* srcA0 = A  + (size_t)(m0 + row0) * HH + sl0 * 8;
    const bf16* srcA1 = A  + (size_t)(m0 + row1) * HH + sl1 * 8;
    const bf16* srcB0 = Bt + (size_t)(n0 + row0) * HH + sl0 * 8;
    const bf16* srcB1 = Bt + (size_t)(n0 + row1) * HH + sl1 * 8;

    for (int k0 = 0; k0 < HH; k0 += 32) {
        GLDS(srcA0 + k0, dstA0);
        GLDS(srcA1 + k0, dstA1);
        GLDS(srcB0 + k0, dstB0);
        GLDS(srcB1 + k0, dstB1);
        __syncthreads();
        bf16x8 a[4], b[4];
        #pragma unroll
        for (int i = 0; i < 4; ++i) {
            int ar = wm * 64 + i * 16 + lq;
            a[i] = *(const bf16x8*)&As[ar * 32 + ((kg ^ (ar & 3)) * 8)];
        }
        #pragma unroll
        for (int j = 0; j < 4; ++j) {
            int br = wn * 64 + j * 16 + lq;
            b[j] = *(const bf16x8*)&Bs[br * 32 + ((kg ^ (br & 3)) * 8)];
        }
        #pragma unroll
        for (int i = 0; i < 4; ++i)
            #pragma unroll
            for (int j = 0; j < 4; ++j)
                acc[i][j] = __builtin_amdgcn_mfma_f32_16x16x32_bf16(a[i], b[j], acc[i][j], 0, 0, 0);
        __syncthreads();
    }

    // ---- epilogue (a): bias + per-row (this wave's 64-col half) max/sumexp
    const int ct = blockIdx.x * 2 + wn;   // 64-col tile index (race-free)
    float bj[4];
    #pragma unroll
    for (int j = 0; j < 4; ++j) bj[j] = bias[n0 + wn * 64 + j * 16 + lq];
    #pragma unroll
    for (int i = 0; i < 4; ++i) {
        #pragma unroll
        for (int r = 0; r < 4; ++r) {
            float v[4], mx = -3.4e38f;
            #pragma unroll
            for (int j = 0; j < 4; ++j) { v[j] = acc[i][j][r] + bj[j]; mx = fmaxf(mx, v[j]); }
            mx = row16_max(mx);
            float sm = 0.f;
            #pragma unroll
            for (int j = 0; j < 4; ++j) sm += __expf(v[j] - mx);
            sm = row16_sum(sm);
            if (lq == 0) {
                int rowg = m0 + wm * 64 + i * 16 + kg * 4 + r;
                size_t o = ((size_t)rowg * NT64 + ct) * 2;
                part[o] = mx; part[o + 1] = sm;
            }
        }
    }

    // ---- epilogue (b): scatter label columns -> glpT[b][j][t] (scalar stores)
    const int bidx = m0 >> 9;               // sample (512 rows per sample)
    const int t0s  = (m0 & 511) + wm * 64;  // base t for this wave
    const int nbase = n0 + wn * 64;
    for (int j = 0; j < JJ; ++j) {
        int c = (j == 0) ? 0 : ys[bidx * LL + j - 1];   // uniform
        int local = c - nbase;
        if (local >= 0 && local < 64) {     // uniform branch (~2 hits/wave)
            int cl = local & 15;
            float bc = bias[c];
            #pragma unroll
            for (int jt = 0; jt < 4; ++jt) {   // static jt: keep acc in regs
                if ((local >> 4) == jt && lq == cl) {
                    #pragma unroll
                    for (int i = 0; i < 4; ++i)
                        #pragma unroll
                        for (int r = 0; r < 4; ++r) {
                            int tt = t0s + i * 16 + kg * 4 + r;
                            glpT[(size_t)(bidx * JJ + j) * TT + tt] = acc[i][jt][r] + bc;
                        }
                }
            }
        }
    }
}

// ---------------------------------------------------------------------------
// Kernel 2: fused tail. One block per sample (16 x 256 threads).
// Wave 0: register DP (linear domain, exact pow2 rescale, pipelined loads).
// Waves 1-3: per-sample sum of lse over t < Tin, straight from `part`
//   (each 16-lane group owns one row; DPP row16 reductions).
// One barrier; lane 0 does device-scope atomicAdd into out (zeroed by prep).
// ---------------------------------------------------------------------------
#define F4AT(arr, u) ( ((u) & 3) == 0 ? arr[(u) >> 2].x \
                     : ((u) & 3) == 1 ? arr[(u) >> 2].y \
                     : ((u) & 3) == 2 ? arr[(u) >> 2].z : arr[(u) >> 2].w )

#define LOADI(p0v, pBv, blk) { \
    int bb_ = (blk); bb_ = bb_ < 32 ? bb_ : 31; \
    const float4* p0_ = (const float4*)(g0 + bb_ * 16); \
    const float4* pB_ = (const float4*)(gB + bb_ * 16); \
    p0v[0] = p0_[0]; p0v[1] = p0_[1]; p0v[2] = p0_[2]; p0v[3] = p0_[3]; \
    pBv[0] = pB_[0]; pBv[1] = pB_[1]; pBv[2] = pB_[2]; pBv[3] = pB_[3]; \
}

#define RVCOMP(rv, p0v, pBv, blk) { \
    const int tB_ = (blk) * 16; \
    _Pragma("unroll") \
    for (int u = 0; u < 16; ++u) { \
        rv[u] = __builtin_amdgcn_exp2f((F4AT(pBv, u) - F4AT(p0v, u)) * LOG2E); \
    } \
    if (tB_ > 0 && tB_ + 16 <= Tin) { \
        float s_ = 0.f; \
        _Pragma("unroll") \
        for (int u = 0; u < 16; ++u) s_ += F4AT(p0v, u); \
        corr += s_; \
    } else { \
        float s_ = 0.f; \
        _Pragma("unroll") \
        for (int u = 0; u < 16; ++u) { \
            int t_ = tB_ + u; \
            s_ += (t_ >= 1 && t_ < Tin) ? F4AT(p0v, u) : 0.f; \
        } \
        corr += s_; \
    } }

#define RESCALE() { \
        float m_ = fmaxf(fmaxf(vA ? A : 0.f, vB ? B : 0.f), vC ? C : 0.f); \
        m_ = dpp_max_t<0x111>(m_); /* row_shr:1 */ \
        m_ = dpp_max_t<0x112>(m_); /* row_shr:2 */ \
        m_ = dpp_max_t<0x114>(m_); /* row_shr:4 */ \
        m_ = dpp_max_t<0x118>(m_); /* row_shr:8 */ \
        m_ = dpp_max_t<0x142>(m_); /* row_bcast:15 */ \
        m_ = dpp_max_t<0x143>(m_); /* row_bcast:31 */ \
        int mb = __builtin_amdgcn_readlane(__float_as_int(m_), 63); \
        int k_ = ((mb >> 23) & 0xFF) - 127; \
        float sc = __int_as_float((127 - k_) << 23); \
        A *= sc; B *= sc; C *= sc; K += k_; \
    }

#define DO16N(rv, blk) { \
    const int tB_ = (blk) * 16; \
    if (tB_ > 0 && tB_ + 16 <= Tin) { \
        _Pragma("unroll") \
        for (int u = 0; u < 16; ++u) { \
            float prevB = dpp_shr1_zero(B); \
            float nA = A + prevB; \
            float t1 = A + B; \
            float t2 = skipB ? prevB : 0.f; \
            float nB = (t1 + t2) * rv[u]; \
            float nC = C + B; \
            A = nA; B = nB; C = nC; \
            if (u == 7 || u == 15) RESCALE(); \
        } \
    } else { \
        _Pragma("unroll") \
        for (int u = 0; u < 16; ++u) { \
            int t_ = tB_ + u; \
            bool upd = (t_ >= 1) && (t_ < Tin); \
            float prevB = dpp_shr1_zero(B); \
            float nA = A + prevB; \
            float t1 = A + B; \
            float t2 = skipB ? prevB : 0.f; \
            float nB = (t1 + t2) * rv[u]; \
            float nC = C + B; \
            A = upd ? nA : A; B = upd ? nB : B; C = upd ? nC : C; \
            if (u == 7 || u == 15) RESCALE(); \
        } \
    } }

__global__ __launch_bounds__(256) void ctc_tail(
    const float* __restrict__ glpT, const float* __restrict__ part,
    const int* __restrict__ ys, const int* __restrict__ hs_lens,
    const int* __restrict__ ys_lens, float* __restrict__ out)
{
    __shared__ float lsum_sh[4];
    const int b = blockIdx.x;
    const int tid = threadIdx.x;
    const int wave = tid >> 6;
    const int lane = tid & 63;
    const int Tin = hs_lens[b];
    const int Ll  = ys_lens[b];         // 32..64

    float v1 = 0.f, v2 = 0.f, corr = 0.f;
    int K = 0;

    if (wave == 0) {
        // ---------------- wave 0: the DP ----------------
        const int l = lane;
        const float* g0 = glpT + (size_t)(b * JJ) * TT;            // blank row
        const float* gB = glpT + (size_t)(b * JJ + l + 1) * TT;    // label row

        const bool vA = (l <= Ll);
        const bool vB = (l <  Ll);
        const bool vC = (l == 63) && (Ll == 64);

        int cc = ys[b * LL + l];
        bool skipB = false;
        if (l >= 1) { int cp = ys[b * LL + l - 1]; skipB = (cc != 0) && (cc != cp); }

        float raw0_0 = g0[0];
        float d0 = (gB[0] - raw0_0) * LOG2E;
        float A = (l == 0) ? 1.0f : 0.0f;
        float B = (l == 0) ? __builtin_amdgcn_exp2f(d0) : 0.0f;
        float C = 0.0f;
        corr = raw0_0;

        float4 p0a[4], pBa[4], p0b[4], pBb[4];
        float rva[16], rvb[16];
        LOADI(p0a, pBa, 0);
        LOADI(p0b, pBb, 1);
        for (int blk = 0; blk < 32; blk += 2) {
            RVCOMP(rva, p0a, pBa, blk);
            LOADI(p0a, pBa, blk + 2);
            DO16N(rva, blk);
            RVCOMP(rvb, p0b, pBb, blk + 1);
            LOADI(p0b, pBb, blk + 3);
            DO16N(rvb, blk + 1);
            if (16 * (blk + 2) >= Tin) break;
        }

        v1 = (Ll == 64) ? __shfl(C, 63, 64) : __shfl(A, Ll, 64);  // ah[2Ll]
        v2 = __shfl(B, Ll - 1, 64);                                // ah[2Ll-1]
    } else {
        // ---------------- waves 1-3: sum of lse over t < Tin ----------------
        const int t0 = (wave - 1) * 171;
        const int t1 = (t0 + 171 < TT) ? (t0 + 171) : TT;
        const int grp = lane >> 4, li = lane & 15;
        float lsum = 0.f;
        for (int t = t0 + grp; t < t1; t += 4) {
            const float* p = part + ((size_t)(b * TT + t)) * (NT64 * 2) + li * 8;
            float4 a  = ((const float4*)p)[0];
            float4 c4 = ((const float4*)p)[1];
            // four (max,sum) pairs per lane
            float ml = fmaxf(fmaxf(a.x, a.z), fmaxf(c4.x, c4.z));
            float sl = a.y  * __expf(a.x  - ml) + a.w  * __expf(a.z  - ml)
                     + c4.y * __expf(c4.x - ml) + c4.w * __expf(c4.z - ml);
            float wm = row16_max(ml);
            float ss = row16_sum(sl * __expf(ml - wm));
            if (li == 0 && t < Tin) lsum += wm + logf(ss);
        }
        // butterfly sum (only li==0 lanes carry nonzero)
        #pragma unroll
        for (int d = 1; d < 64; d <<= 1) lsum += __shfl_xor(lsum, d);
        if (lane == 0) lsum_sh[wave] = lsum;
    }
    __syncthreads();
    if (tid == 0) {
        float lsumT = lsum_sh[1] + lsum_sh[2] + lsum_sh[3];
        float ll2 = __builtin_amdgcn_logf(v1 + v2) + (float)K + (corr - lsumT) * LOG2E;
        atomicAdd(out, (-ll2 * LN2) * (1.0f / (float)BB));
    }
}

// ---------------------------------------------------------------------------
extern "C" void kernel_launch(void* const* d_in, const int* in_sizes, int n_in,
                              void* d_out, int out_size, void* d_ws, size_t ws_size,
                              hipStream_t stream) {
    const float* hs      = (const float*)d_in[0];   // [16,512,512] f32
    const int*   hs_lens = (const int*)  d_in[1];   // [16]
    const int*   ys      = (const int*)  d_in[2];   // [16,64]
    const int*   ys_lens = (const int*)  d_in[3];   // [16]
    const float* W       = (const float*)d_in[4];   // [512,4096] f32
    const float* bias    = (const float*)d_in[5];   // [4096]
    float* out = (float*)d_out;

    float* ws   = (float*)d_ws;
    float* part = ws;                                // M*NT64*2 = 1048576 f
    float* glpT = part + (size_t)MM * NT64 * 2;      // B*J*T = 532480 f
    bf16*  Abf  = (bf16*)(glpT + (size_t)BB * JJ * TT);  // 4194304 bf16
    bf16*  Wt   = Abf + (size_t)MM * HH;             // 2097152 bf16

    prep<<<4608, 256, 0, stream>>>(hs, W, Abf, Wt, out);
    gemm_lse_mfma<<<dim3(VV / TN, MM / 128), 256, 0, stream>>>(Abf, Wt, bias, ys, part, glpT);
    ctc_tail<<<BB, 256, 0, stream>>>(glpT, part, ys, hs_lens, ys_lens, out);
}

// Round 12
// 179.932 us; speedup vs baseline: 4.8209x; 1.0183x over previous
//
#include <hip/hip_runtime.h>
#include <hip/hip_bf16.h>
#include <math.h>

// Sizes (fixed by the problem)
#define BB   16
#define TT   512
#define HH   512
#define VV   4096
#define LL   64
#define SS   129           // 2*L+1
#define JJ   65            // distinct symbols per sample: blank + L labels
#define MM   (BB*TT)       // 8192 GEMM rows

#define LOG2E 1.4426950408889634f
#define LN2   0.6931471805599453f

typedef __bf16 bf16;
typedef __attribute__((ext_vector_type(4))) __bf16 bf16x4;
typedef __attribute__((ext_vector_type(8))) __bf16 bf16x8;
typedef __attribute__((ext_vector_type(4))) float f32x4;

// DPP helpers ---------------------------------------------------------------
template<int CTRL>
__device__ __forceinline__ float dpp_mov(float x) {   // moved value (all lanes valid)
    return __int_as_float(__builtin_amdgcn_update_dpp(
        __float_as_int(x), __float_as_int(x), CTRL, 0xF, 0xF, false));
}
__device__ __forceinline__ float row16_max(float x) {
    x = fmaxf(x, dpp_mov<0x128>(x));  // row_ror:8
    x = fmaxf(x, dpp_mov<0x124>(x));  // row_ror:4
    x = fmaxf(x, dpp_mov<0x122>(x));  // row_ror:2
    x = fmaxf(x, dpp_mov<0x121>(x));  // row_ror:1
    return x;
}
__device__ __forceinline__ float row16_sum(float x) {
    x += dpp_mov<0x128>(x);
    x += dpp_mov<0x124>(x);
    x += dpp_mov<0x122>(x);
    x += dpp_mov<0x121>(x);
    return x;
}
__device__ __forceinline__ float dpp_shr1_zero(float x) {  // wave shift; lane0 -> 0
    int r = __builtin_amdgcn_update_dpp(0, __float_as_int(x),
                                        0x138 /*wave_shr:1*/, 0xF, 0xF, false);
    return __int_as_float(r);
}
template<int CTRL>
__device__ __forceinline__ float dpp_max_t(float m) {
    int r = __builtin_amdgcn_update_dpp(0, __float_as_int(m), CTRL, 0xF, 0xF, false);
    return fmaxf(m, __int_as_float(r));
}

// ---------------------------------------------------------------------------
// Kernel 0: fused prep. Blocks [0,4096): hs f32 -> Abf bf16.
// Blocks [4096,4608): W [K][N] f32 -> Wt [N][K] bf16 (64x64 LDS transpose).
// Block 0 thread 0 also zeroes out[0] (stream-ordered before ctc_tail's atomics).
// ---------------------------------------------------------------------------
__global__ __launch_bounds__(256) void prep(const float* __restrict__ hs,
                                            const float* __restrict__ W,
                                            bf16* __restrict__ Abf,
                                            bf16* __restrict__ Wt,
                                            float* __restrict__ out)
{
    __shared__ float t[64][65];
    const int tid = threadIdx.x;
    int bx = blockIdx.x;
    if (bx == 0 && tid == 0) out[0] = 0.f;
    if (bx < 4096) {
        int idx = bx * 256 + tid;            // one float4 per thread
        float4 v = ((const float4*)hs)[idx];
        bf16x4 o = {(bf16)v.x, (bf16)v.y, (bf16)v.z, (bf16)v.w};
        *(bf16x4*)(Abf + (size_t)idx * 4) = o;
    } else {
        bx -= 4096;
        const int n0 = (bx & 63) * 64;
        const int k0 = (bx >> 6) * 64;
        #pragma unroll
        for (int i = 0; i < 16; ++i) {
            int idx = tid + i * 256;
            int kk = idx >> 6, nn = idx & 63;
            t[kk][nn] = W[(size_t)(k0 + kk) * VV + n0 + nn];
        }
        __syncthreads();
        #pragma unroll
        for (int i = 0; i < 16; ++i) {
            int idx = tid + i * 256;
            int nl = idx >> 6, kk = idx & 63;
            Wt[(size_t)(n0 + nl) * HH + k0 + kk] = (bf16)t[kk][nl];
        }
    }
}

// ---------------------------------------------------------------------------
// Kernel 1: bf16 MFMA GEMM + LSE partials + label-column scatter.
// SWIZZLE FIX (r12): slot involution is  s ^= (row>>1)&3  (was row&3, which
// left 4-way bank conflicts: lanes {0,4,8,12} of each issue group shared a
// bank quartet). With (row>>1)&3, each 8-lane group covers all 32 banks once.
// Applied on BOTH sides: pre-swizzled global source + swizzled ds_read slot.
// ---------------------------------------------------------------------------
#define TN 128
#define NT64 (VV / 64)     // 64 column-tiles of width 64

#define GLDS(src, dst) \
    __builtin_amdgcn_global_load_lds((const __attribute__((address_space(1))) void*)(src), \
                                     (__attribute__((address_space(3))) void*)(dst), 16, 0, 0)

__global__ __launch_bounds__(256) void gemm_lse_mfma(
    const bf16* __restrict__ A,    // [M][512] bf16
    const bf16* __restrict__ Bt,   // [N=4096][512] bf16 (W transposed)
    const float* __restrict__ bias,
    const int*  __restrict__ ys,   // [BB][LL]
    float* __restrict__ part,      // [M][NT64][2] (max, sumexp)
    float* __restrict__ glpT)      // [BB][JJ][TT] raw label logits + bias
{
    __shared__ bf16 As[128 * 32];
    __shared__ bf16 Bs[128 * 32];
    const int tid = threadIdx.x;
    const int lane = tid & 63;
    const int wid = tid >> 6;
    const int wm = wid >> 1, wn = wid & 1;
    const int m0 = blockIdx.y * 128, n0 = blockIdx.x * 128;
    const int lq = lane & 15, kg = lane >> 4;

    f32x4 acc[4][4];
    const f32x4 z = {0.f, 0.f, 0.f, 0.f};
    #pragma unroll
    for (int i = 0; i < 4; ++i)
        #pragma unroll
        for (int j = 0; j < 4; ++j) acc[i][j] = z;

    const int c0 = tid;
    const int row0 = c0 >> 2, sl0 = (c0 & 3) ^ ((row0 >> 1) & 3);
    const int c1 = tid + 256;
    const int row1 = c1 >> 2, sl1 = (c1 & 3) ^ ((row1 >> 1) & 3);
    bf16* dstA0 = As + (size_t)(0 * 256 + (tid & 192)) * 8;
    bf16* dstA1 = As + (size_t)(1 * 256 + (tid & 192)) * 8;
    bf16* dstB0 = Bs + (size_t)(0 * 256 + (tid & 192)) * 8;
    bf16* dstB1 = Bs + (size_t)(1 * 256 + (tid & 192)) * 8;
    const bf16* srcA0 = A  + (size_t)(m0 + row0) * HH + sl0 * 8;
    const bf16* srcA1 = A  + (size_t)(m0 + row1) * HH + sl1 * 8;
    const bf16* srcB0 = Bt + (size_t)(n0 + row0) * HH + sl0 * 8;
    const bf16* srcB1 = Bt + (size_t)(n0 + row1) * HH + sl1 * 8;

    for (int k0 = 0; k0 < HH; k0 += 32) {
        GLDS(srcA0 + k0, dstA0);
        GLDS(srcA1 + k0, dstA1);
        GLDS(srcB0 + k0, dstB0);
        GLDS(srcB1 + k0, dstB1);
        __syncthreads();
        bf16x8 a[4], b[4];
        #pragma unroll
        for (int i = 0; i < 4; ++i) {
            int ar = wm * 64 + i * 16 + lq;
            a[i] = *(const bf16x8*)&As[ar * 32 + ((kg ^ ((ar >> 1) & 3)) * 8)];
        }
        #pragma unroll
        for (int j = 0; j < 4; ++j) {
            int br = wn * 64 + j * 16 + lq;
            b[j] = *(const bf16x8*)&Bs[br * 32 + ((kg ^ ((br >> 1) & 3)) * 8)];
        }
        #pragma unroll
        for (int i = 0; i < 4; ++i)
            #pragma unroll
            for (int j = 0; j < 4; ++j)
                acc[i][j] = __builtin_amdgcn_mfma_f32_16x16x32_bf16(a[i], b[j], acc[i][j], 0, 0, 0);
        __syncthreads();
    }

    // ---- epilogue (a): bias + per-row (this wave's 64-col half) max/sumexp
    const int ct = blockIdx.x * 2 + wn;   // 64-col tile index (race-free)
    float bj[4];
    #pragma unroll
    for (int j = 0; j < 4; ++j) bj[j] = bias[n0 + wn * 64 + j * 16 + lq];
    #pragma unroll
    for (int i = 0; i < 4; ++i) {
        #pragma unroll
        for (int r = 0; r < 4; ++r) {
            float v[4], mx = -3.4e38f;
            #pragma unroll
            for (int j = 0; j < 4; ++j) { v[j] = acc[i][j][r] + bj[j]; mx = fmaxf(mx, v[j]); }
            mx = row16_max(mx);
            float sm = 0.f;
            #pragma unroll
            for (int j = 0; j < 4; ++j) sm += __expf(v[j] - mx);
            sm = row16_sum(sm);
            if (lq == 0) {
                int rowg = m0 + wm * 64 + i * 16 + kg * 4 + r;
                size_t o = ((size_t)rowg * NT64 + ct) * 2;
                part[o] = mx; part[o + 1] = sm;
            }
        }
    }

    // ---- epilogue (b): scatter label columns -> glpT[b][j][t] (scalar stores)
    const int bidx = m0 >> 9;               // sample (512 rows per sample)
    const int t0s  = (m0 & 511) + wm * 64;  // base t for this wave
    const int nbase = n0 + wn * 64;
    for (int j = 0; j < JJ; ++j) {
        int c = (j == 0) ? 0 : ys[bidx * LL + j - 1];   // uniform
        int local = c - nbase;
        if (local >= 0 && local < 64) {     // uniform branch (~2 hits/wave)
            int cl = local & 15;
            float bc = bias[c];
            #pragma unroll
            for (int jt = 0; jt < 4; ++jt) {   // static jt: keep acc in regs
                if ((local >> 4) == jt && lq == cl) {
                    #pragma unroll
                    for (int i = 0; i < 4; ++i)
                        #pragma unroll
                        for (int r = 0; r < 4; ++r) {
                            int tt = t0s + i * 16 + kg * 4 + r;
                            glpT[(size_t)(bidx * JJ + j) * TT + tt] = acc[i][jt][r] + bc;
                        }
                }
            }
        }
    }
}

// ---------------------------------------------------------------------------
// Kernel 2: fused tail. One block per sample (16 x 256 threads).
// Wave 0: register DP (linear domain, exact pow2 rescale). Emission buffers
// are NAMED float4 registers (r12: rule-#20 insurance against scratch spill).
// Waves 1-3: per-sample sum of lse from `part`. One barrier; atomicAdd out.
// ---------------------------------------------------------------------------
#define LOADN(pA0,pA1,pA2,pA3,qA0,qA1,qA2,qA3, blk) { \
    int bb_ = (blk); bb_ = bb_ < 32 ? bb_ : 31; \
    const float4* p0_ = (const float4*)(g0 + bb_ * 16); \
    const float4* pB_ = (const float4*)(gB + bb_ * 16); \
    pA0 = p0_[0]; pA1 = p0_[1]; pA2 = p0_[2]; pA3 = p0_[3]; \
    qA0 = pB_[0]; qA1 = pB_[1]; qA2 = pB_[2]; qA3 = pB_[3]; }

#define RV4(rv, base, p4, q4) \
    rv[base+0] = __builtin_amdgcn_exp2f((q4.x - p4.x) * LOG2E); \
    rv[base+1] = __builtin_amdgcn_exp2f((q4.y - p4.y) * LOG2E); \
    rv[base+2] = __builtin_amdgcn_exp2f((q4.z - p4.z) * LOG2E); \
    rv[base+3] = __builtin_amdgcn_exp2f((q4.w - p4.w) * LOG2E);

#define CSUM(p4) (((p4).x + (p4).y) + ((p4).z + (p4).w))
#define CMSK(p4, tb) \
    ( (((tb)+0 >= 1) && ((tb)+0 < Tin) ? (p4).x : 0.f) \
    + (((tb)+1 >= 1) && ((tb)+1 < Tin) ? (p4).y : 0.f) \
    + (((tb)+2 >= 1) && ((tb)+2 < Tin) ? (p4).z : 0.f) \
    + (((tb)+3 >= 1) && ((tb)+3 < Tin) ? (p4).w : 0.f) )

#define RVCN(rv, pA0,pA1,pA2,pA3,qA0,qA1,qA2,qA3, blk) { \
    const int tB_ = (blk) * 16; \
    RV4(rv, 0,  pA0, qA0); RV4(rv, 4,  pA1, qA1); \
    RV4(rv, 8,  pA2, qA2); RV4(rv, 12, pA3, qA3); \
    if (tB_ > 0 && tB_ + 16 <= Tin) { \
        corr += (CSUM(pA0) + CSUM(pA1)) + (CSUM(pA2) + CSUM(pA3)); \
    } else { \
        corr += (CMSK(pA0, tB_) + CMSK(pA1, tB_ + 4)) \
              + (CMSK(pA2, tB_ + 8) + CMSK(pA3, tB_ + 12)); \
    } }

#define RESCALE() { \
        float m_ = fmaxf(fmaxf(vA ? A : 0.f, vB ? B : 0.f), vC ? C : 0.f); \
        m_ = dpp_max_t<0x111>(m_); /* row_shr:1 */ \
        m_ = dpp_max_t<0x112>(m_); /* row_shr:2 */ \
        m_ = dpp_max_t<0x114>(m_); /* row_shr:4 */ \
        m_ = dpp_max_t<0x118>(m_); /* row_shr:8 */ \
        m_ = dpp_max_t<0x142>(m_); /* row_bcast:15 */ \
        m_ = dpp_max_t<0x143>(m_); /* row_bcast:31 */ \
        int mb = __builtin_amdgcn_readlane(__float_as_int(m_), 63); \
        int k_ = ((mb >> 23) & 0xFF) - 127; \
        float sc = __int_as_float((127 - k_) << 23); \
        A *= sc; B *= sc; C *= sc; K += k_; \
    }

#define DO16N(rv, blk) { \
    const int tB_ = (blk) * 16; \
    if (tB_ > 0 && tB_ + 16 <= Tin) { \
        _Pragma("unroll") \
        for (int u = 0; u < 16; ++u) { \
            float prevB = dpp_shr1_zero(B); \
            float nA = A + prevB; \
            float t1 = A + B; \
            float t2 = skipB ? prevB : 0.f; \
            float nB = (t1 + t2) * rv[u]; \
            float nC = C + B; \
            A = nA; B = nB; C = nC; \
            if (u == 7 || u == 15) RESCALE(); \
        } \
    } else { \
        _Pragma("unroll") \
        for (int u = 0; u < 16; ++u) { \
            int t_ = tB_ + u; \
            bool upd = (t_ >= 1) && (t_ < Tin); \
            float prevB = dpp_shr1_zero(B); \
            float nA = A + prevB; \
            float t1 = A + B; \
            float t2 = skipB ? prevB : 0.f; \
            float nB = (t1 + t2) * rv[u]; \
            float nC = C + B; \
            A = upd ? nA : A; B = upd ? nB : B; C = upd ? nC : C; \
            if (u == 7 || u == 15) RESCALE(); \
        } \
    } }

__global__ __launch_bounds__(256) void ctc_tail(
    const float* __restrict__ glpT, const float* __restrict__ part,
    const int* __restrict__ ys, const int* __restrict__ hs_lens,
    const int* __restrict__ ys_lens, float* __restrict__ out)
{
    __shared__ float lsum_sh[4];
    const int b = blockIdx.x;
    const int tid = threadIdx.x;
    const int wave = tid >> 6;
    const int lane = tid & 63;
    const int Tin = hs_lens[b];
    const int Ll  = ys_lens[b];         // 32..64

    float v1 = 0.f, v2 = 0.f, corr = 0.f;
    int K = 0;

    if (wave == 0) {
        // ---------------- wave 0: the DP ----------------
        const int l = lane;
        const float* g0 = glpT + (size_t)(b * JJ) * TT;            // blank row
        const float* gB = glpT + (size_t)(b * JJ + l + 1) * TT;    // label row

        const bool vA = (l <= Ll);
        const bool vB = (l <  Ll);
        const bool vC = (l == 63) && (Ll == 64);

        int cc = ys[b * LL + l];
        bool skipB = false;
        if (l >= 1) { int cp = ys[b * LL + l - 1]; skipB = (cc != 0) && (cc != cp); }

        float raw0_0 = g0[0];
        float d0 = (gB[0] - raw0_0) * LOG2E;
        float A = (l == 0) ? 1.0f : 0.0f;
        float B = (l == 0) ? __builtin_amdgcn_exp2f(d0) : 0.0f;
        float C = 0.0f;
        corr = raw0_0;

        float4 pa0, pa1, pa2, pa3, qa0, qa1, qa2, qa3;
        float4 pb0, pb1, pb2, pb3, qb0, qb1, qb2, qb3;
        float rva[16], rvb[16];
        LOADN(pa0,pa1,pa2,pa3,qa0,qa1,qa2,qa3, 0);
        LOADN(pb0,pb1,pb2,pb3,qb0,qb1,qb2,qb3, 1);
        for (int blk = 0; blk < 32; blk += 2) {
            RVCN(rva, pa0,pa1,pa2,pa3,qa0,qa1,qa2,qa3, blk);
            LOADN(pa0,pa1,pa2,pa3,qa0,qa1,qa2,qa3, blk + 2);
            DO16N(rva, blk);
            RVCN(rvb, pb0,pb1,pb2,pb3,qb0,qb1,qb2,qb3, blk + 1);
            LOADN(pb0,pb1,pb2,pb3,qb0,qb1,qb2,qb3, blk + 3);
            DO16N(rvb, blk + 1);
            if (16 * (blk + 2) >= Tin) break;
        }

        v1 = (Ll == 64) ? __shfl(C, 63, 64) : __shfl(A, Ll, 64);  // ah[2Ll]
        v2 = __shfl(B, Ll - 1, 64);                                // ah[2Ll-1]
    } else {
        // ---------------- waves 1-3: sum of lse over t < Tin ----------------
        const int t0 = (wave - 1) * 171;
        const int t1 = (t0 + 171 < TT) ? (t0 + 171) : TT;
        const int grp = lane >> 4, li = lane & 15;
        float lsum = 0.f;
        for (int t = t0 + grp; t < t1; t += 4) {
            const float* p = part + ((size_t)(b * TT + t)) * (NT64 * 2) + li * 8;
            float4 a  = ((const float4*)p)[0];
            float4 c4 = ((const float4*)p)[1];
            float ml = fmaxf(fmaxf(a.x, a.z), fmaxf(c4.x, c4.z));
            float sl = a.y  * __expf(a.x  - ml) + a.w  * __expf(a.z  - ml)
                     + c4.y * __expf(c4.x - ml) + c4.w * __expf(c4.z - ml);
            float wm = row16_max(ml);
            float ss = row16_sum(sl * __expf(ml - wm));
            if (li == 0 && t < Tin) lsum += wm + logf(ss);
        }
        #pragma unroll
        for (int d = 1; d < 64; d <<= 1) lsum += __shfl_xor(lsum, d);
        if (lane == 0) lsum_sh[wave] = lsum;
    }
    __syncthreads();
    if (tid == 0) {
        float lsumT = lsum_sh[1] + lsum_sh[2] + lsum_sh[3];
        float ll2 = __builtin_amdgcn_logf(v1 + v2) + (float)K + (corr - lsumT) * LOG2E;
        atomicAdd(out, (-ll2 * LN2) * (1.0f / (float)BB));
    }
}

// ---------------------------------------------------------------------------
extern "C" void kernel_launch(void* const* d_in, const int* in_sizes, int n_in,
                              void* d_out, int out_size, void* d_ws, size_t ws_size,
                              hipStream_t stream) {
    const float* hs      = (const float*)d_in[0];   // [16,512,512] f32
    const int*   hs_lens = (const int*)  d_in[1];   // [16]
    const int*   ys      = (const int*)  d_in[2];   // [16,64]
    const int*   ys_lens = (const int*)  d_in[3];   // [16]
    const float* W       = (const float*)d_in[4];   // [512,4096] f32
    const float* bias    = (const float*)d_in[5];   // [4096]
    float* out = (float*)d_out;

    float* ws   = (float*)d_ws;
    float* part = ws;                                // M*NT64*2 = 1048576 f
    float* glpT = part + (size_t)MM * NT64 * 2;      // B*J*T = 532480 f
    bf16*  Abf  = (bf16*)(glpT + (size_t)BB * JJ * TT);  // 4194304 bf16
    bf16*  Wt   = Abf + (size_t)MM * HH;             // 2097152 bf16

    prep<<<4608, 256, 0, stream>>>(hs, W, Abf, Wt, out);
    gemm_lse_mfma<<<dim3(VV / TN, MM / 128), 256, 0, stream>>>(Abf, Wt, bias, ys, part, glpT);
    ctc_tail<<<BB, 256, 0, stream>>>(glpT, part, ys, hs_lens, ys_lens, out);
}